// Round 3
// baseline (212.470 us; speedup 1.0000x reference)
//
#include <hip/hip_runtime.h>
#include <math.h>

#define EPSV 1.1920929e-07f

typedef __attribute__((ext_vector_type(8))) short short8;
typedef __attribute__((ext_vector_type(4))) float f32x4;

__device__ __forceinline__ float bf2f(unsigned short u) {
    union { unsigned int i; float f; } c; c.i = ((unsigned int)u) << 16; return c.f;
}
__device__ __forceinline__ unsigned short f2bf(float f) {
    union { float f; unsigned int i; } c; c.f = f;
    unsigned int r = c.i + 0x7FFFu + ((c.i >> 16) & 1u);   // RNE
    return (unsigned short)(r >> 16);
}
// pack two f32 -> two bf16 (round-half-up) in one u32: low=a, high=b
__device__ __forceinline__ unsigned int pack_bf16_ru(float a, float b) {
    union { float f; unsigned int i; } ca, cb; ca.f = a; cb.f = b;
    return __builtin_amdgcn_perm(cb.i + 0x8000u, ca.i + 0x8000u, 0x07060302u);
}
// async global -> LDS, 16 B per lane (dest = wave-uniform base + lane*16)
__device__ __forceinline__ void async_lds16(const unsigned short* g, unsigned short* l) {
    __builtin_amdgcn_global_load_lds(
        (const __attribute__((address_space(1))) unsigned int*)g,
        (__attribute__((address_space(3))) unsigned int*)l, 16, 0, 0);
}

// ======================================================================
// cast fp32 -> bf16 elementwise. 4 elems/thread.
// ======================================================================
__global__ __launch_bounds__(256) void cast_bf16(
    const float* __restrict__ src, unsigned short* __restrict__ dst, int n)
{
    const int i = (blockIdx.x * 256 + threadIdx.x) * 4;
    if (i >= n) return;
    const float4 v = *(const float4*)&src[i];
    ushort4 o;
    o.x = f2bf(v.x); o.y = f2bf(v.y); o.z = f2bf(v.z); o.w = f2bf(v.w);
    *(ushort4*)&dst[i] = o;
}

// ======================================================================
// transpose + cast for BOTH weights in one launch:
// W_attn [1024][3072] -> Wat [3072][1024]; W_proj [1024][1024] -> Wpt.
// ======================================================================
__global__ __launch_bounds__(256) void transpose_cast_both(
    const float* __restrict__ Wa, unsigned short* __restrict__ Wat,
    const float* __restrict__ Wp, unsigned short* __restrict__ Wpt)
{
    __shared__ float tile[32][33];
    int bx = blockIdx.x;
    const float* W; unsigned short* Wt; int N;
    if (bx < 96) { W = Wa; Wt = Wat; N = 3072; }
    else         { W = Wp; Wt = Wpt; N = 1024; bx -= 96; }
    const int n0 = bx * 32, k0 = blockIdx.y * 32;
    const int r = threadIdx.x >> 3, c4 = (threadIdx.x & 7) * 4;
    const float4 v = *(const float4*)&W[(size_t)(k0 + r) * N + n0 + c4];
    tile[r][c4 + 0] = v.x; tile[r][c4 + 1] = v.y;
    tile[r][c4 + 2] = v.z; tile[r][c4 + 3] = v.w;
    __syncthreads();
    ushort4 o;
    o.x = f2bf(tile[c4 + 0][r]); o.y = f2bf(tile[c4 + 1][r]);
    o.z = f2bf(tile[c4 + 2][r]); o.w = f2bf(tile[c4 + 3][r]);
    *(ushort4*)&Wt[(size_t)(n0 + r) * 1024 + k0 + c4] = o;
}

// ======================================================================
// bf16 MFMA GEMM, m97 structure + BK=64. C = A @ Bt^T + bias.
// ======================================================================
template <bool OUT_BF16>
__global__ __launch_bounds__(256) void gemm_bf16(
    const unsigned short* __restrict__ A,
    const unsigned short* __restrict__ Bt,
    const float* __restrict__ bias,
    void* __restrict__ Cv,
    int M, int N, int K)
{
    __shared__ unsigned short As0[128][32], As1[128][32];
    __shared__ unsigned short Bs0[128][32], Bs1[128][32];
    const int t    = threadIdx.x;
    const int lane = t & 63;
    const int wv   = t >> 6;
    const int wrow = (wv >> 1) * 64;
    const int wcol = (wv & 1) * 64;
    const int m0 = blockIdx.y * 128;
    const int n0 = blockIdx.x * 128;
    const int col  = lane & 15;
    const int quad = lane >> 4;

    const int srow = (wv << 5) + (lane >> 2);     // wv*32 + 0..15
    const int scol = (lane & 3) << 3;             // 0,8,16,24
    const unsigned short* a00 = A  + (size_t)(m0 + srow) * K + scol;
    const unsigned short* a10 = a00 + (size_t)16 * K;
    const unsigned short* a01 = a00 + 32;
    const unsigned short* a11 = a10 + 32;
    const unsigned short* b00 = Bt + (size_t)(n0 + srow) * K + scol;
    const unsigned short* b10 = b00 + (size_t)16 * K;
    const unsigned short* b01 = b00 + 32;
    const unsigned short* b11 = b10 + 32;
    unsigned short* al0 = &As0[srow][scol];
    unsigned short* al1 = &As0[srow + 16][scol];
    unsigned short* al2 = &As1[srow][scol];
    unsigned short* al3 = &As1[srow + 16][scol];
    unsigned short* bl0 = &Bs0[srow][scol];
    unsigned short* bl1 = &Bs0[srow + 16][scol];
    unsigned short* bl2 = &Bs1[srow][scol];
    unsigned short* bl3 = &Bs1[srow + 16][scol];

    f32x4 acc[4][4];
    #pragma unroll
    for (int i = 0; i < 4; ++i)
        #pragma unroll
        for (int j = 0; j < 4; ++j)
            acc[i][j] = (f32x4){0.f, 0.f, 0.f, 0.f};

    for (int k0 = 0; k0 < K; k0 += 64) {
        async_lds16(a00, al0);
        async_lds16(a10, al1);
        async_lds16(a01, al2);
        async_lds16(a11, al3);
        async_lds16(b00, bl0);
        async_lds16(b10, bl1);
        async_lds16(b01, bl2);
        async_lds16(b11, bl3);
        a00 += 64; a10 += 64; a01 += 64; a11 += 64;
        b00 += 64; b10 += 64; b01 += 64; b11 += 64;
        __syncthreads();
        short8 af[2][4], bf[2][4];
        #pragma unroll
        for (int mt = 0; mt < 4; ++mt) {
            af[0][mt] = *(const short8*)&As0[wrow + mt * 16 + col][quad << 3];
            af[1][mt] = *(const short8*)&As1[wrow + mt * 16 + col][quad << 3];
        }
        #pragma unroll
        for (int nt = 0; nt < 4; ++nt) {
            bf[0][nt] = *(const short8*)&Bs0[wcol + nt * 16 + col][quad << 3];
            bf[1][nt] = *(const short8*)&Bs1[wcol + nt * 16 + col][quad << 3];
        }
        #pragma unroll
        for (int ks = 0; ks < 2; ++ks)
            #pragma unroll
            for (int mt = 0; mt < 4; ++mt)
                #pragma unroll
                for (int nt = 0; nt < 4; ++nt)
                    acc[mt][nt] = __builtin_amdgcn_mfma_f32_16x16x32_bf16(
                        af[ks][mt], bf[ks][nt], acc[mt][nt], 0, 0, 0);
        __syncthreads();
    }

    const int rowq = quad << 2;
    #pragma unroll
    for (int nt = 0; nt < 4; ++nt) {
        const int n = n0 + wcol + nt * 16 + col;
        const float bv = bias[n];
        #pragma unroll
        for (int mt = 0; mt < 4; ++mt) {
            #pragma unroll
            for (int r = 0; r < 4; ++r) {
                const int m = m0 + wrow + mt * 16 + rowq + r;
                const float v = acc[mt][nt][r] + bv;
                if (OUT_BF16)
                    ((unsigned short*)Cv)[(size_t)m * N + n] = f2bf(v);
                else
                    ((float*)Cv)[(size_t)m * N + n] = v;
            }
        }
    }
}

// ======================================================================
// bf16 MFMA GEMM, 128(M) x 64(N), BK=64 (skinny-N gemm2). fp32 out.
// ======================================================================
__global__ __launch_bounds__(256) void gemm_bf16_n64(
    const unsigned short* __restrict__ A,
    const unsigned short* __restrict__ Bt,
    const float* __restrict__ bias,
    float* __restrict__ C,
    int M, int N, int K)
{
    __shared__ unsigned short As0[128][32], As1[128][32];
    __shared__ unsigned short Bs0[64][32], Bs1[64][32];
    const int t    = threadIdx.x;
    const int lane = t & 63;
    const int wv   = t >> 6;
    const int wrow = wv << 5;
    const int m0 = blockIdx.y * 128;
    const int n0 = blockIdx.x * 64;
    const int col  = lane & 15;
    const int quad = lane >> 4;

    const int srow = (wv << 5) + (lane >> 2);
    const int scol = (lane & 3) << 3;
    const unsigned short* a00 = A  + (size_t)(m0 + srow) * K + scol;
    const unsigned short* a10 = a00 + (size_t)16 * K;
    const unsigned short* a01 = a00 + 32;
    const unsigned short* a11 = a10 + 32;
    const int bsrow = (wv << 4) + (lane >> 2);
    const unsigned short* b00 = Bt + (size_t)(n0 + bsrow) * K + scol;
    const unsigned short* b01 = b00 + 32;
    unsigned short* al0 = &As0[srow][scol];
    unsigned short* al1 = &As0[srow + 16][scol];
    unsigned short* al2 = &As1[srow][scol];
    unsigned short* al3 = &As1[srow + 16][scol];
    unsigned short* bl0 = &Bs0[bsrow][scol];
    unsigned short* bl1 = &Bs1[bsrow][scol];

    f32x4 acc[2][4];
    #pragma unroll
    for (int i = 0; i < 2; ++i)
        #pragma unroll
        for (int j = 0; j < 4; ++j)
            acc[i][j] = (f32x4){0.f, 0.f, 0.f, 0.f};

    for (int k0 = 0; k0 < K; k0 += 64) {
        async_lds16(a00, al0);
        async_lds16(a10, al1);
        async_lds16(a01, al2);
        async_lds16(a11, al3);
        async_lds16(b00, bl0);
        async_lds16(b01, bl1);
        a00 += 64; a10 += 64; a01 += 64; a11 += 64;
        b00 += 64; b01 += 64;
        __syncthreads();
        short8 af[2][2], bf[2][4];
        #pragma unroll
        for (int mt = 0; mt < 2; ++mt) {
            af[0][mt] = *(const short8*)&As0[wrow + mt * 16 + col][quad << 3];
            af[1][mt] = *(const short8*)&As1[wrow + mt * 16 + col][quad << 3];
        }
        #pragma unroll
        for (int nt = 0; nt < 4; ++nt) {
            bf[0][nt] = *(const short8*)&Bs0[nt * 16 + col][quad << 3];
            bf[1][nt] = *(const short8*)&Bs1[nt * 16 + col][quad << 3];
        }
        #pragma unroll
        for (int ks = 0; ks < 2; ++ks)
            #pragma unroll
            for (int mt = 0; mt < 2; ++mt)
                #pragma unroll
                for (int nt = 0; nt < 4; ++nt)
                    acc[mt][nt] = __builtin_amdgcn_mfma_f32_16x16x32_bf16(
                        af[ks][mt], bf[ks][nt], acc[mt][nt], 0, 0, 0);
        __syncthreads();
    }

    const int rowq = quad << 2;
    #pragma unroll
    for (int nt = 0; nt < 4; ++nt) {
        const int n = n0 + nt * 16 + col;
        const float bv = bias[n];
        #pragma unroll
        for (int mt = 0; mt < 2; ++mt) {
            #pragma unroll
            for (int r = 0; r < 4; ++r) {
                const int m = m0 + wrow + mt * 16 + rowq + r;
                C[(size_t)m * N + n] = acc[mt][nt][r] + bv;
            }
        }
    }
}

// ======================================================================
// RMSNorm (D=64) then rotary, in-place on bf16 q/k slices.
// ======================================================================
__global__ __launch_bounds__(256) void rmsnorm_rope(
    unsigned short* __restrict__ qkv, const float* __restrict__ cosp,
    const float* __restrict__ sinp, int BT, int T)
{
    const int wid  = (blockIdx.x << 2) + (threadIdx.x >> 6);
    const int lane = threadIdx.x & 63;
    const int hq = wid & 3;
    const int w  = (wid >> 2) & 1;
    const int bt = wid >> 3;
    if (bt >= BT) return;
    const int h  = (hq << 2) + (lane >> 4);
    const int d4 = (lane & 15) << 2;
    const int tpos = bt % T;
    const size_t idx = (size_t)bt * 3072 + (w << 10) + (h << 6) + d4;

    const ushort4 u = *(const ushort4*)&qkv[idx];
    const float x0 = bf2f(u.x), x1 = bf2f(u.y), x2 = bf2f(u.z), x3 = bf2f(u.w);
    float ss = x0 * x0 + x1 * x1 + x2 * x2 + x3 * x3;
    ss += __shfl_xor(ss, 1, 64);
    ss += __shfl_xor(ss, 2, 64);
    ss += __shfl_xor(ss, 4, 64);
    ss += __shfl_xor(ss, 8, 64);
    const float rn = rsqrtf(ss * (1.0f / 64.0f) + EPSV);
    const float xn0 = x0 * rn, xn1 = x1 * rn, xn2 = x2 * rn, xn3 = x3 * rn;
    const float p0 = __shfl_xor(xn0, 8, 64);
    const float p1 = __shfl_xor(xn1, 8, 64);
    const float p2 = __shfl_xor(xn2, 8, 64);
    const float p3 = __shfl_xor(xn3, 8, 64);
    const float sgn = (d4 < 32) ? -1.0f : 1.0f;
    const float4 c = *(const float4*)&cosp[tpos * 64 + d4];
    const float4 s = *(const float4*)&sinp[tpos * 64 + d4];
    const float scale = (w == 0) ? 0.18033688011112042f : 1.0f;  // log2e/8
    ushort4 o;
    o.x = f2bf(fmaf(xn0, c.x, sgn * p0 * s.x) * scale);
    o.y = f2bf(fmaf(xn1, c.y, sgn * p1 * s.y) * scale);
    o.z = f2bf(fmaf(xn2, c.z, sgn * p2 * s.z) * scale);
    o.w = f2bf(fmaf(xn3, c.w, sgn * p3 * s.w) * scale);
    *(ushort4*)&qkv[idx] = o;
}

// ======================================================================
// V transpose: qkv v-slice [b,t,h,d] -> vt [b,h,d,t]. 64x64 tiles.
// ======================================================================
__global__ __launch_bounds__(256) void v_transpose(
    const unsigned short* __restrict__ qkv, unsigned short* __restrict__ vt,
    int T)
{
    __shared__ unsigned short tile[64][72];
    const int bh = blockIdx.x;
    const int b  = bh >> 4, h = bh & 15;
    const int t0 = blockIdx.y << 6;
    const int t  = threadIdx.x;
    const unsigned short* vbase = qkv + (size_t)b * T * 3072 + 2048 + (h << 6);

    #pragma unroll
    for (int i = 0; i < 2; ++i) {
        const int c = t + (i << 8);
        const int r = c >> 3, c8 = (c & 7) << 3;
        const short8 v = *(const short8*)&vbase[(size_t)(t0 + r) * 3072 + c8];
        #pragma unroll
        for (int j = 0; j < 8; ++j)
            tile[c8 + j][r] = (unsigned short)v[j];
    }
    __syncthreads();
    #pragma unroll
    for (int i = 0; i < 2; ++i) {
        const int c = t + (i << 8);
        const int d = c >> 3, c8 = (c & 7) << 3;
        const short8 o = *(const short8*)&tile[d][c8];
        *(short8*)&vt[((size_t)bh * 64 + d) * T + t0 + c8] = o;
    }
}

// ======================================================================
// MFMA flash attention, FIXED-MAX softmax, q-tile 128.
// Round-3: 512 threads = 8 waves = 4 q-groups x 2 K-SPLIT parities.
// Wave (qg,s) computes only tiles kt%2==s for its 32 q-rows; fixed-max
// softmax makes partials combine trivially at the end (O=O0+O1, l=l0+l1)
// -- one LDS reduction per block, not per iter. This doubles waves/SIMD
// (latency hiding; R2 was dependency-latency-bound at 2 waves/SIMD with
// all pipes <30% busy) while keeping per-CU LDS traffic unchanged.
// Staging: 512 threads share one 64x64 K+V stage -> 2 asyncs/thread,
// double-buffered, one barrier per tile, XOR source-swizzle (R2).
// ======================================================================
__global__ __launch_bounds__(512, 4) void flash_attn_mfma(
    const unsigned short* __restrict__ qkv,
    const unsigned short* __restrict__ vt,
    unsigned short* __restrict__ yb,
    int B, int T)
{
    const int bh = blockIdx.x;
    const int b  = bh >> 4, h = bh & 15;
    const int ny = (int)gridDim.y;
    const int y  = (int)blockIdx.y;
    const int hny = (ny + 1) >> 1;
    const int jq = (y < hny) ? (ny - 1 - y) : (y - hny);   // balanced pairing
    const int q0 = jq << 7;
    const int t  = threadIdx.x;
    const int lane = t & 63;
    const int w    = t >> 6;       // 0..7
    const int qg   = w >> 1;       // q-group 0..3
    const int sp   = w & 1;        // k-split parity
    const int col  = lane & 15;
    const int quad = lane >> 4;

    // [0,8192): Kb[2][64][64]  [8192,16384): Vb[2][64][64]
    // [16384,34816): Ps[8][32][72]        (total 69632 B)
    __shared__ __align__(16) unsigned short smem[34816];
    unsigned short* Kb = smem;
    unsigned short* Vb = smem + 8192;
    unsigned short* Ps = smem + 16384;

    const unsigned short* qb  = qkv + (size_t)b * T * 3072 + (h << 6);
    const unsigned short* kb  = qb + 1024;
    const unsigned short* vtb = vt + (size_t)bh * 64 * T;

    const int qw  = q0 + (qg << 5);      // wave's first q row (32 rows)
    const int qg0 = qw + col;
    const int qg1 = qw + 16 + col;

    short8 qf[2][2];   // [qc][ks]
    {
        const unsigned short* qrow0 = qb + (size_t)qg0 * 3072 + (quad << 3);
        qf[0][0] = *(const short8*)&qrow0[0];
        qf[0][1] = *(const short8*)&qrow0[32];
        const unsigned short* qrow1 = qb + (size_t)qg1 * 3072 + (quad << 3);
        qf[1][0] = *(const short8*)&qrow1[0];
        qf[1][1] = *(const short8*)&qrow1[32];
    }

    f32x4 oacc[2][4];
    #pragma unroll
    for (int qc = 0; qc < 2; ++qc)
        #pragma unroll
        for (int i = 0; i < 4; ++i) oacc[qc][i] = (f32x4){0.f, 0.f, 0.f, 0.f};
    float l_i[2] = {0.f, 0.f};

    // ---- async staging: 512 threads, 1 K + 1 V load each ----
    const int sr = t >> 3;                         // row 0..63
    const int sg = (((t & 7) ^ (sr & 7)) << 3);    // swizzled chunk * 8 elems
    const unsigned short* kp = kb  + (size_t)sr * 3072 + sg;
    const unsigned short* vp = vtb + (size_t)sr * T + sg;

    // prologue: tile 0 -> buffer 0
    async_lds16(kp, Kb + (t << 3));
    async_lds16(vp, Vb + (t << 3));
    kp += (size_t)64 * 3072; vp += 64;

    // per-lane swizzled chunk element-offsets for fragment reads
    const int cs0 = ((quad ^ (col & 7)) << 3);
    const int cs1 = (((4 + quad) ^ (col & 7)) << 3);

    const int last_kt = (q0 + 127) >> 6;
    int cur = 0;
    for (int kt = 0; kt <= last_kt; ++kt) {
        const int k0 = kt << 6;
        __syncthreads();   // drains async -> buf[cur] ready; prev compute done
        if (kt < last_kt) {
            async_lds16(kp, Kb + ((cur ^ 1) << 12) + (t << 3));
            async_lds16(vp, Vb + ((cur ^ 1) << 12) + (t << 3));
            kp += (size_t)64 * 3072; vp += 64;
        }

        // k-split: this wave computes only its parity; skip masked tiles
        if (((kt & 1) == sp) && (k0 <= qw + 31)) {
            const unsigned short* Kc = Kb + (cur << 12);
            const unsigned short* Vc = Vb + (cur << 12);

            // ---- S^T = K @ Q^T ----
            f32x4 st[2][4];
            #pragma unroll
            for (int qc = 0; qc < 2; ++qc)
                #pragma unroll
                for (int i = 0; i < 4; ++i) st[qc][i] = (f32x4){0.f, 0.f, 0.f, 0.f};
            __builtin_amdgcn_s_setprio(1);
            #pragma unroll
            for (int ks = 0; ks < 2; ++ks)
                #pragma unroll
                for (int mt = 0; mt < 4; ++mt) {
                    const short8 kf = *(const short8*)&Kc[(mt * 16 + col) * 64 + (ks ? cs1 : cs0)];
                    st[0][mt] = __builtin_amdgcn_mfma_f32_16x16x32_bf16(kf, qf[0][ks], st[0][mt], 0, 0, 0);
                    st[1][mt] = __builtin_amdgcn_mfma_f32_16x16x32_bf16(kf, qf[1][ks], st[1][mt], 0, 0, 0);
                }
            __builtin_amdgcn_s_setprio(0);

            // ---- fixed-max softmax: p = exp2(s), mask via exp2(-inf)=0 ----
            #pragma unroll
            for (int qc = 0; qc < 2; ++qc) {
                const int qg_ = qw + (qc << 4) + col;
                const bool diag = (k0 + 63 > qw + (qc << 4));
                unsigned short* pw = Ps + ((w << 5) + (qc << 4) + col) * 72;
                float rs = 0.f;
                #pragma unroll
                for (int mt = 0; mt < 4; ++mt) {
                    float x0 = st[qc][mt][0], x1 = st[qc][mt][1];
                    float x2 = st[qc][mt][2], x3 = st[qc][mt][3];
                    if (diag) {
                        const int sbase = k0 + mt * 16 + (quad << 2);
                        if (sbase + 0 > qg_) x0 = -INFINITY;
                        if (sbase + 1 > qg_) x1 = -INFINITY;
                        if (sbase + 2 > qg_) x2 = -INFINITY;
                        if (sbase + 3 > qg_) x3 = -INFINITY;
                    }
                    const float p0 = __builtin_amdgcn_exp2f(x0);
                    const float p1 = __builtin_amdgcn_exp2f(x1);
                    const float p2 = __builtin_amdgcn_exp2f(x2);
                    const float p3 = __builtin_amdgcn_exp2f(x3);
                    rs += (p0 + p1) + (p2 + p3);
                    uint2 pk;
                    pk.x = pack_bf16_ru(p0, p1);
                    pk.y = pack_bf16_ru(p2, p3);
                    *(uint2*)&pw[mt * 16 + (quad << 2)] = pk;
                }
                rs += __shfl_xor(rs, 16, 64);
                rs += __shfl_xor(rs, 32, 64);
                l_i[qc] += rs;
            }

            // ---- O^T += V^T @ P^T ----
            __builtin_amdgcn_s_setprio(1);
            #pragma unroll
            for (int ks = 0; ks < 2; ++ks) {
                const short8 pf0 = *(const short8*)&Ps[((w << 5) + col) * 72 + ks * 32 + (quad << 3)];
                const short8 pf1 = *(const short8*)&Ps[((w << 5) + 16 + col) * 72 + ks * 32 + (quad << 3)];
                #pragma unroll
                for (int mt = 0; mt < 4; ++mt) {
                    const short8 vf = *(const short8*)&Vc[(mt * 16 + col) * 64 + (ks ? cs1 : cs0)];
                    oacc[0][mt] = __builtin_amdgcn_mfma_f32_16x16x32_bf16(vf, pf0, oacc[0][mt], 0, 0, 0);
                    oacc[1][mt] = __builtin_amdgcn_mfma_f32_16x16x32_bf16(vf, pf1, oacc[1][mt], 0, 0, 0);
                }
            }
            __builtin_amdgcn_s_setprio(0);
        }
        cur ^= 1;
    }

    // ---- combine k-split partials via LDS, then store ----
    __syncthreads();                       // all compute done, Kb/Vb free
    float* Of = (float*)smem;              // [4][64][36] f32 = 36864 B
    float* Lf = ((float*)smem) + 9216;     // 512 B at byte 36864
    if (sp) {
        float* orow = Of + (((qg << 6) + lane) * 36);
        #pragma unroll
        for (int qc = 0; qc < 2; ++qc)
            #pragma unroll
            for (int mt = 0; mt < 4; ++mt)
                *(f32x4*)&orow[(qc << 4) + (mt << 2)] = oacc[qc][mt];
        if (quad == 0) {
            Lf[(qg << 5) + col] = l_i[0];
            Lf[(qg << 5) + 16 + col] = l_i[1];
        }
    }
    __syncthreads();
    if (!sp) {
        const float* orow = Of + (((qg << 6) + lane) * 36);
        const float inv0 = 1.0f / (l_i[0] + Lf[(qg << 5) + col]);
        const float inv1 = 1.0f / (l_i[1] + Lf[(qg << 5) + 16 + col]);
        unsigned short* yrow0 = yb + (size_t)(b * T + qg0) * 1024 + (h << 6);
        unsigned short* yrow1 = yb + (size_t)(b * T + qg1) * 1024 + (h << 6);
        #pragma unroll
        for (int mt = 0; mt < 4; ++mt) {
            const f32x4 p0 = *(const f32x4*)&orow[(mt << 2)];
            const f32x4 p1 = *(const f32x4*)&orow[16 + (mt << 2)];
            ushort4 yv0, yv1;
            yv0.x = f2bf((oacc[0][mt][0] + p0[0]) * inv0);
            yv0.y = f2bf((oacc[0][mt][1] + p0[1]) * inv0);
            yv0.z = f2bf((oacc[0][mt][2] + p0[2]) * inv0);
            yv0.w = f2bf((oacc[0][mt][3] + p0[3]) * inv0);
            yv1.x = f2bf((oacc[1][mt][0] + p1[0]) * inv1);
            yv1.y = f2bf((oacc[1][mt][1] + p1[1]) * inv1);
            yv1.z = f2bf((oacc[1][mt][2] + p1[2]) * inv1);
            yv1.w = f2bf((oacc[1][mt][3] + p1[3]) * inv1);
            *(ushort4*)&yrow0[mt * 16 + (quad << 2)] = yv0;
            *(ushort4*)&yrow1[mt * 16 + (quad << 2)] = yv1;
        }
    }
}

// ======================================================================
extern "C" void kernel_launch(void* const* d_in, const int* in_sizes, int n_in,
                              void* d_out, int out_size, void* d_ws, size_t ws_size,
                              hipStream_t stream)
{
    const float* x      = (const float*)d_in[0];
    const float* cosp   = (const float*)d_in[1];
    const float* sinp   = (const float*)d_in[2];
    const float* W_attn = (const float*)d_in[3];
    const float* b_attn = (const float*)d_in[4];
    const float* W_proj = (const float*)d_in[5];
    const float* b_proj = (const float*)d_in[6];
    float* out = (float*)d_out;

    const int C = 1024, H = 16;
    const int T  = in_sizes[1] / 64;     // cos: (T, 64)
    const int BT = in_sizes[0] / C;      // B*T
    const int B  = BT / T;

    unsigned short* qkvb = (unsigned short*)d_ws;              // BT*3072
    unsigned short* xb   = qkvb + (size_t)BT * 3072;           // BT*1024
    unsigned short* Wab  = xb   + (size_t)BT * 1024;           // 3072*1024
    unsigned short* Wpb  = Wab  + (size_t)3072 * 1024;         // 1024*1024
    unsigned short* yb   = Wpb  + (size_t)1024 * 1024;         // BT*1024
    unsigned short* vtb  = xb;   // vt aliases xb (x dead after gemm1)

    cast_bf16<<<dim3(BT * C / 1024), dim3(256), 0, stream>>>(x, xb, BT * C);
    transpose_cast_both<<<dim3(128, 32), dim3(256), 0, stream>>>(
        W_attn, Wab, W_proj, Wpb);

    gemm_bf16<true><<<dim3(3 * C / 128, BT / 128), dim3(256), 0, stream>>>(
        xb, Wab, b_attn, qkvb, BT, 3 * C, C);

    rmsnorm_rope<<<dim3(BT * 2), dim3(256), 0, stream>>>(
        qkvb, cosp, sinp, BT, T);

    v_transpose<<<dim3(B * H, T / 64), dim3(256), 0, stream>>>(qkvb, vtb, T);

    flash_attn_mfma<<<dim3(B * H, T / 128), dim3(512), 0, stream>>>(
        qkvb, vtb, yb, B, T);

    gemm_bf16_n64<<<dim3(C / 64, BT / 128), dim3(256), 0, stream>>>(
        yb, Wpb, b_proj, out, BT, C, C);
}

// Round 4
// 189.561 us; speedup vs baseline: 1.1208x; 1.1208x over previous
//
#include <hip/hip_runtime.h>
#include <math.h>

#define EPSV 1.1920929e-07f

typedef __attribute__((ext_vector_type(8))) short short8;
typedef __attribute__((ext_vector_type(4))) float f32x4;

__device__ __forceinline__ float bf2f(unsigned short u) {
    union { unsigned int i; float f; } c; c.i = ((unsigned int)u) << 16; return c.f;
}
__device__ __forceinline__ unsigned short f2bf(float f) {
    union { float f; unsigned int i; } c; c.f = f;
    unsigned int r = c.i + 0x7FFFu + ((c.i >> 16) & 1u);   // RNE
    return (unsigned short)(r >> 16);
}
// pack two f32 -> two bf16 (round-half-up) in one u32: low=a, high=b
__device__ __forceinline__ unsigned int pack_bf16_ru(float a, float b) {
    union { float f; unsigned int i; } ca, cb; ca.f = a; cb.f = b;
    return __builtin_amdgcn_perm(cb.i + 0x8000u, ca.i + 0x8000u, 0x07060302u);
}
// async global -> LDS, 16 B per lane (dest = wave-uniform base + lane*16)
__device__ __forceinline__ void async_lds16(const unsigned short* g, unsigned short* l) {
    __builtin_amdgcn_global_load_lds(
        (const __attribute__((address_space(1))) unsigned int*)g,
        (__attribute__((address_space(3))) unsigned int*)l, 16, 0, 0);
}

// ======================================================================
// cast fp32 -> bf16 elementwise. 4 elems/thread.
// ======================================================================
__global__ __launch_bounds__(256) void cast_bf16(
    const float* __restrict__ src, unsigned short* __restrict__ dst, int n)
{
    const int i = (blockIdx.x * 256 + threadIdx.x) * 4;
    if (i >= n) return;
    const float4 v = *(const float4*)&src[i];
    ushort4 o;
    o.x = f2bf(v.x); o.y = f2bf(v.y); o.z = f2bf(v.z); o.w = f2bf(v.w);
    *(ushort4*)&dst[i] = o;
}

// ======================================================================
// transpose + cast for BOTH weights in one launch:
// W_attn [1024][3072] -> Wat [3072][1024]; W_proj [1024][1024] -> Wpt.
// ======================================================================
__global__ __launch_bounds__(256) void transpose_cast_both(
    const float* __restrict__ Wa, unsigned short* __restrict__ Wat,
    const float* __restrict__ Wp, unsigned short* __restrict__ Wpt)
{
    __shared__ float tile[32][33];
    int bx = blockIdx.x;
    const float* W; unsigned short* Wt; int N;
    if (bx < 96) { W = Wa; Wt = Wat; N = 3072; }
    else         { W = Wp; Wt = Wpt; N = 1024; bx -= 96; }
    const int n0 = bx * 32, k0 = blockIdx.y * 32;
    const int r = threadIdx.x >> 3, c4 = (threadIdx.x & 7) * 4;
    const float4 v = *(const float4*)&W[(size_t)(k0 + r) * N + n0 + c4];
    tile[r][c4 + 0] = v.x; tile[r][c4 + 1] = v.y;
    tile[r][c4 + 2] = v.z; tile[r][c4 + 3] = v.w;
    __syncthreads();
    ushort4 o;
    o.x = f2bf(tile[c4 + 0][r]); o.y = f2bf(tile[c4 + 1][r]);
    o.z = f2bf(tile[c4 + 2][r]); o.w = f2bf(tile[c4 + 3][r]);
    *(ushort4*)&Wt[(size_t)(n0 + r) * 1024 + k0 + c4] = o;
}

// ======================================================================
// bf16 MFMA GEMM, m97 structure + BK=64. C = A @ Bt^T + bias.
// ======================================================================
template <bool OUT_BF16>
__global__ __launch_bounds__(256) void gemm_bf16(
    const unsigned short* __restrict__ A,
    const unsigned short* __restrict__ Bt,
    const float* __restrict__ bias,
    void* __restrict__ Cv,
    int M, int N, int K)
{
    __shared__ unsigned short As0[128][32], As1[128][32];
    __shared__ unsigned short Bs0[128][32], Bs1[128][32];
    const int t    = threadIdx.x;
    const int lane = t & 63;
    const int wv   = t >> 6;
    const int wrow = (wv >> 1) * 64;
    const int wcol = (wv & 1) * 64;
    const int m0 = blockIdx.y * 128;
    const int n0 = blockIdx.x * 128;
    const int col  = lane & 15;
    const int quad = lane >> 4;

    const int srow = (wv << 5) + (lane >> 2);     // wv*32 + 0..15
    const int scol = (lane & 3) << 3;             // 0,8,16,24
    const unsigned short* a00 = A  + (size_t)(m0 + srow) * K + scol;
    const unsigned short* a10 = a00 + (size_t)16 * K;
    const unsigned short* a01 = a00 + 32;
    const unsigned short* a11 = a10 + 32;
    const unsigned short* b00 = Bt + (size_t)(n0 + srow) * K + scol;
    const unsigned short* b10 = b00 + (size_t)16 * K;
    const unsigned short* b01 = b00 + 32;
    const unsigned short* b11 = b10 + 32;
    unsigned short* al0 = &As0[srow][scol];
    unsigned short* al1 = &As0[srow + 16][scol];
    unsigned short* al2 = &As1[srow][scol];
    unsigned short* al3 = &As1[srow + 16][scol];
    unsigned short* bl0 = &Bs0[srow][scol];
    unsigned short* bl1 = &Bs0[srow + 16][scol];
    unsigned short* bl2 = &Bs1[srow][scol];
    unsigned short* bl3 = &Bs1[srow + 16][scol];

    f32x4 acc[4][4];
    #pragma unroll
    for (int i = 0; i < 4; ++i)
        #pragma unroll
        for (int j = 0; j < 4; ++j)
            acc[i][j] = (f32x4){0.f, 0.f, 0.f, 0.f};

    for (int k0 = 0; k0 < K; k0 += 64) {
        async_lds16(a00, al0);
        async_lds16(a10, al1);
        async_lds16(a01, al2);
        async_lds16(a11, al3);
        async_lds16(b00, bl0);
        async_lds16(b10, bl1);
        async_lds16(b01, bl2);
        async_lds16(b11, bl3);
        a00 += 64; a10 += 64; a01 += 64; a11 += 64;
        b00 += 64; b10 += 64; b01 += 64; b11 += 64;
        __syncthreads();
        short8 af[2][4], bf[2][4];
        #pragma unroll
        for (int mt = 0; mt < 4; ++mt) {
            af[0][mt] = *(const short8*)&As0[wrow + mt * 16 + col][quad << 3];
            af[1][mt] = *(const short8*)&As1[wrow + mt * 16 + col][quad << 3];
        }
        #pragma unroll
        for (int nt = 0; nt < 4; ++nt) {
            bf[0][nt] = *(const short8*)&Bs0[wcol + nt * 16 + col][quad << 3];
            bf[1][nt] = *(const short8*)&Bs1[wcol + nt * 16 + col][quad << 3];
        }
        #pragma unroll
        for (int ks = 0; ks < 2; ++ks)
            #pragma unroll
            for (int mt = 0; mt < 4; ++mt)
                #pragma unroll
                for (int nt = 0; nt < 4; ++nt)
                    acc[mt][nt] = __builtin_amdgcn_mfma_f32_16x16x32_bf16(
                        af[ks][mt], bf[ks][nt], acc[mt][nt], 0, 0, 0);
        __syncthreads();
    }

    const int rowq = quad << 2;
    #pragma unroll
    for (int nt = 0; nt < 4; ++nt) {
        const int n = n0 + wcol + nt * 16 + col;
        const float bv = bias[n];
        #pragma unroll
        for (int mt = 0; mt < 4; ++mt) {
            #pragma unroll
            for (int r = 0; r < 4; ++r) {
                const int m = m0 + wrow + mt * 16 + rowq + r;
                const float v = acc[mt][nt][r] + bv;
                if (OUT_BF16)
                    ((unsigned short*)Cv)[(size_t)m * N + n] = f2bf(v);
                else
                    ((float*)Cv)[(size_t)m * N + n] = v;
            }
        }
    }
}

// ======================================================================
// bf16 MFMA GEMM, 128(M) x 64(N), BK=64 (skinny-N gemm2). fp32 out.
// ======================================================================
__global__ __launch_bounds__(256) void gemm_bf16_n64(
    const unsigned short* __restrict__ A,
    const unsigned short* __restrict__ Bt,
    const float* __restrict__ bias,
    float* __restrict__ C,
    int M, int N, int K)
{
    __shared__ unsigned short As0[128][32], As1[128][32];
    __shared__ unsigned short Bs0[64][32], Bs1[64][32];
    const int t    = threadIdx.x;
    const int lane = t & 63;
    const int wv   = t >> 6;
    const int wrow = wv << 5;
    const int m0 = blockIdx.y * 128;
    const int n0 = blockIdx.x * 64;
    const int col  = lane & 15;
    const int quad = lane >> 4;

    const int srow = (wv << 5) + (lane >> 2);
    const int scol = (lane & 3) << 3;
    const unsigned short* a00 = A  + (size_t)(m0 + srow) * K + scol;
    const unsigned short* a10 = a00 + (size_t)16 * K;
    const unsigned short* a01 = a00 + 32;
    const unsigned short* a11 = a10 + 32;
    const int bsrow = (wv << 4) + (lane >> 2);
    const unsigned short* b00 = Bt + (size_t)(n0 + bsrow) * K + scol;
    const unsigned short* b01 = b00 + 32;
    unsigned short* al0 = &As0[srow][scol];
    unsigned short* al1 = &As0[srow + 16][scol];
    unsigned short* al2 = &As1[srow][scol];
    unsigned short* al3 = &As1[srow + 16][scol];
    unsigned short* bl0 = &Bs0[bsrow][scol];
    unsigned short* bl1 = &Bs1[bsrow][scol];

    f32x4 acc[2][4];
    #pragma unroll
    for (int i = 0; i < 2; ++i)
        #pragma unroll
        for (int j = 0; j < 4; ++j)
            acc[i][j] = (f32x4){0.f, 0.f, 0.f, 0.f};

    for (int k0 = 0; k0 < K; k0 += 64) {
        async_lds16(a00, al0);
        async_lds16(a10, al1);
        async_lds16(a01, al2);
        async_lds16(a11, al3);
        async_lds16(b00, bl0);
        async_lds16(b01, bl1);
        a00 += 64; a10 += 64; a01 += 64; a11 += 64;
        b00 += 64; b01 += 64;
        __syncthreads();
        short8 af[2][2], bf[2][4];
        #pragma unroll
        for (int mt = 0; mt < 2; ++mt) {
            af[0][mt] = *(const short8*)&As0[wrow + mt * 16 + col][quad << 3];
            af[1][mt] = *(const short8*)&As1[wrow + mt * 16 + col][quad << 3];
        }
        #pragma unroll
        for (int nt = 0; nt < 4; ++nt) {
            bf[0][nt] = *(const short8*)&Bs0[nt * 16 + col][quad << 3];
            bf[1][nt] = *(const short8*)&Bs1[nt * 16 + col][quad << 3];
        }
        #pragma unroll
        for (int ks = 0; ks < 2; ++ks)
            #pragma unroll
            for (int mt = 0; mt < 2; ++mt)
                #pragma unroll
                for (int nt = 0; nt < 4; ++nt)
                    acc[mt][nt] = __builtin_amdgcn_mfma_f32_16x16x32_bf16(
                        af[ks][mt], bf[ks][nt], acc[mt][nt], 0, 0, 0);
        __syncthreads();
    }

    const int rowq = quad << 2;
    #pragma unroll
    for (int nt = 0; nt < 4; ++nt) {
        const int n = n0 + nt * 16 + col;
        const float bv = bias[n];
        #pragma unroll
        for (int mt = 0; mt < 2; ++mt) {
            #pragma unroll
            for (int r = 0; r < 4; ++r) {
                const int m = m0 + wrow + mt * 16 + rowq + r;
                C[(size_t)m * N + n] = acc[mt][nt][r] + bv;
            }
        }
    }
}

// ======================================================================
// RMSNorm (D=64) then rotary, in-place on bf16 q/k slices.
// ======================================================================
__global__ __launch_bounds__(256) void rmsnorm_rope(
    unsigned short* __restrict__ qkv, const float* __restrict__ cosp,
    const float* __restrict__ sinp, int BT, int T)
{
    const int wid  = (blockIdx.x << 2) + (threadIdx.x >> 6);
    const int lane = threadIdx.x & 63;
    const int hq = wid & 3;
    const int w  = (wid >> 2) & 1;
    const int bt = wid >> 3;
    if (bt >= BT) return;
    const int h  = (hq << 2) + (lane >> 4);
    const int d4 = (lane & 15) << 2;
    const int tpos = bt % T;
    const size_t idx = (size_t)bt * 3072 + (w << 10) + (h << 6) + d4;

    const ushort4 u = *(const ushort4*)&qkv[idx];
    const float x0 = bf2f(u.x), x1 = bf2f(u.y), x2 = bf2f(u.z), x3 = bf2f(u.w);
    float ss = x0 * x0 + x1 * x1 + x2 * x2 + x3 * x3;
    ss += __shfl_xor(ss, 1, 64);
    ss += __shfl_xor(ss, 2, 64);
    ss += __shfl_xor(ss, 4, 64);
    ss += __shfl_xor(ss, 8, 64);
    const float rn = rsqrtf(ss * (1.0f / 64.0f) + EPSV);
    const float xn0 = x0 * rn, xn1 = x1 * rn, xn2 = x2 * rn, xn3 = x3 * rn;
    const float p0 = __shfl_xor(xn0, 8, 64);
    const float p1 = __shfl_xor(xn1, 8, 64);
    const float p2 = __shfl_xor(xn2, 8, 64);
    const float p3 = __shfl_xor(xn3, 8, 64);
    const float sgn = (d4 < 32) ? -1.0f : 1.0f;
    const float4 c = *(const float4*)&cosp[tpos * 64 + d4];
    const float4 s = *(const float4*)&sinp[tpos * 64 + d4];
    const float scale = (w == 0) ? 0.18033688011112042f : 1.0f;  // log2e/8
    ushort4 o;
    o.x = f2bf(fmaf(xn0, c.x, sgn * p0 * s.x) * scale);
    o.y = f2bf(fmaf(xn1, c.y, sgn * p1 * s.y) * scale);
    o.z = f2bf(fmaf(xn2, c.z, sgn * p2 * s.z) * scale);
    o.w = f2bf(fmaf(xn3, c.w, sgn * p3 * s.w) * scale);
    *(ushort4*)&qkv[idx] = o;
}

// ======================================================================
// V transpose: qkv v-slice [b,t,h,d] -> vt [b,h,d,t]. 64x64 tiles.
// ======================================================================
__global__ __launch_bounds__(256) void v_transpose(
    const unsigned short* __restrict__ qkv, unsigned short* __restrict__ vt,
    int T)
{
    __shared__ unsigned short tile[64][72];
    const int bh = blockIdx.x;
    const int b  = bh >> 4, h = bh & 15;
    const int t0 = blockIdx.y << 6;
    const int t  = threadIdx.x;
    const unsigned short* vbase = qkv + (size_t)b * T * 3072 + 2048 + (h << 6);

    #pragma unroll
    for (int i = 0; i < 2; ++i) {
        const int c = t + (i << 8);
        const int r = c >> 3, c8 = (c & 7) << 3;
        const short8 v = *(const short8*)&vbase[(size_t)(t0 + r) * 3072 + c8];
        #pragma unroll
        for (int j = 0; j < 8; ++j)
            tile[c8 + j][r] = (unsigned short)v[j];
    }
    __syncthreads();
    #pragma unroll
    for (int i = 0; i < 2; ++i) {
        const int c = t + (i << 8);
        const int d = c >> 3, c8 = (c & 7) << 3;
        const short8 o = *(const short8*)&tile[d][c8];
        *(short8*)&vt[((size_t)bh * 64 + d) * T + t0 + c8] = o;
    }
}

// ======================================================================
// MFMA flash attention, FIXED-MAX softmax, q-tile 128.
// Round-4: 512 threads = 8 waves, EACH wave owns 16 q-rows and computes
// EVERY unmasked k-tile (no k-split alternation -- R3's parity waves
// just sat at the barrier). 16 q-rows/wave is forced: it is the only
// decomposition giving 4096 total waves = 16/CU = 4/SIMD of latency
// hiding (32 rows/wave caps the chip at 2/SIMD -> R2 latency-bound).
// Per-iter LDS is the R2 level: global_load_lds double-buffer staging
// (no ds_writes, ONE barrier/iter), XOR source-swizzled K/V (conflict-
// free frag reads), 512 threads share the stage (2 asyncs/thread).
// Balanced q-tile pairing keeps per-CU work constant.
// ======================================================================
__global__ __launch_bounds__(512, 4) void flash_attn_mfma(
    const unsigned short* __restrict__ qkv,
    const unsigned short* __restrict__ vt,
    unsigned short* __restrict__ yb,
    int B, int T)
{
    const int bh = blockIdx.x;
    const int b  = bh >> 4, h = bh & 15;
    const int ny = (int)gridDim.y;
    const int y  = (int)blockIdx.y;
    const int hny = (ny + 1) >> 1;
    const int jq = (y < hny) ? (ny - 1 - y) : (y - hny);   // balanced pairing
    const int q0 = jq << 7;
    const int t  = threadIdx.x;
    const int lane = t & 63;
    const int w    = t >> 6;       // 0..7, each owns 16 q-rows
    const int col  = lane & 15;
    const int quad = lane >> 4;

    // [0,8192): Kb[2][64][64]  [8192,16384): Vb[2][64][64]
    // [16384,25600): Ps[8][16][72]          (total 51200 B)
    __shared__ __align__(16) unsigned short smem[25600];
    unsigned short* Kb = smem;
    unsigned short* Vb = smem + 8192;
    unsigned short* Ps = smem + 16384;

    const unsigned short* qb  = qkv + (size_t)b * T * 3072 + (h << 6);
    const unsigned short* kb  = qb + 1024;
    const unsigned short* vtb = vt + (size_t)bh * 64 * T;

    const int qw = q0 + (w << 4);        // wave's first q row (16 rows)
    const int qg = qw + col;             // lane's q row

    short8 qf[2];
    {
        const unsigned short* qrow = qb + (size_t)qg * 3072 + (quad << 3);
        qf[0] = *(const short8*)&qrow[0];
        qf[1] = *(const short8*)&qrow[32];
    }

    f32x4 oacc[4];
    #pragma unroll
    for (int i = 0; i < 4; ++i) oacc[i] = (f32x4){0.f, 0.f, 0.f, 0.f};
    float l_i = 0.f;

    // ---- async staging: 512 threads, 1 K + 1 V load each ----
    const int sr = t >> 3;                         // row 0..63
    const int sg = (((t & 7) ^ (sr & 7)) << 3);    // swizzled chunk * 8 elems
    const unsigned short* kp = kb  + (size_t)sr * 3072 + sg;
    const unsigned short* vp = vtb + (size_t)sr * T + sg;

    // prologue: tile 0 -> buffer 0
    async_lds16(kp, Kb + (t << 3));
    async_lds16(vp, Vb + (t << 3));
    kp += (size_t)64 * 3072; vp += 64;

    // per-lane swizzled chunk element-offsets for fragment reads
    const int cs0 = ((quad ^ (col & 7)) << 3);
    const int cs1 = (((4 + quad) ^ (col & 7)) << 3);

    const int last_kt = (q0 + 127) >> 6;
    int cur = 0;
    for (int kt = 0; kt <= last_kt; ++kt) {
        const int k0 = kt << 6;
        __syncthreads();   // drains async -> buf[cur] ready; prev compute done
        if (kt < last_kt) {
            async_lds16(kp, Kb + ((cur ^ 1) << 12) + (t << 3));
            async_lds16(vp, Vb + ((cur ^ 1) << 12) + (t << 3));
            kp += (size_t)64 * 3072; vp += 64;
        }

        // wave-uniform skip of fully-masked tiles
        if (k0 <= qw + 15) {
            const unsigned short* Kc = Kb + (cur << 12);
            const unsigned short* Vc = Vb + (cur << 12);

            // ---- S^T = K @ Q^T ----
            f32x4 st[4];
            #pragma unroll
            for (int i = 0; i < 4; ++i) st[i] = (f32x4){0.f, 0.f, 0.f, 0.f};
            __builtin_amdgcn_s_setprio(1);
            #pragma unroll
            for (int ks = 0; ks < 2; ++ks)
                #pragma unroll
                for (int mt = 0; mt < 4; ++mt) {
                    const short8 kf = *(const short8*)&Kc[(mt * 16 + col) * 64 + (ks ? cs1 : cs0)];
                    st[mt] = __builtin_amdgcn_mfma_f32_16x16x32_bf16(kf, qf[ks], st[mt], 0, 0, 0);
                }
            __builtin_amdgcn_s_setprio(0);

            // ---- fixed-max softmax: p = exp2(s), mask via exp2(-inf)=0 ----
            const bool diag = (k0 + 63 > qw);
            unsigned short* pw = Ps + ((w << 4) + col) * 72;
            float rs = 0.f;
            #pragma unroll
            for (int mt = 0; mt < 4; ++mt) {
                float x0 = st[mt][0], x1 = st[mt][1];
                float x2 = st[mt][2], x3 = st[mt][3];
                if (diag) {
                    const int sbase = k0 + mt * 16 + (quad << 2);
                    if (sbase + 0 > qg) x0 = -INFINITY;
                    if (sbase + 1 > qg) x1 = -INFINITY;
                    if (sbase + 2 > qg) x2 = -INFINITY;
                    if (sbase + 3 > qg) x3 = -INFINITY;
                }
                const float p0 = __builtin_amdgcn_exp2f(x0);
                const float p1 = __builtin_amdgcn_exp2f(x1);
                const float p2 = __builtin_amdgcn_exp2f(x2);
                const float p3 = __builtin_amdgcn_exp2f(x3);
                rs += (p0 + p1) + (p2 + p3);
                uint2 pk;
                pk.x = pack_bf16_ru(p0, p1);
                pk.y = pack_bf16_ru(p2, p3);
                *(uint2*)&pw[mt * 16 + (quad << 2)] = pk;
            }
            rs += __shfl_xor(rs, 16, 64);
            rs += __shfl_xor(rs, 32, 64);
            l_i += rs;

            // ---- O^T += V^T @ P^T ----
            __builtin_amdgcn_s_setprio(1);
            #pragma unroll
            for (int ks = 0; ks < 2; ++ks) {
                const short8 pf = *(const short8*)&Ps[((w << 4) + col) * 72 + ks * 32 + (quad << 3)];
                #pragma unroll
                for (int mt = 0; mt < 4; ++mt) {
                    const short8 vf = *(const short8*)&Vc[(mt * 16 + col) * 64 + (ks ? cs1 : cs0)];
                    oacc[mt] = __builtin_amdgcn_mfma_f32_16x16x32_bf16(vf, pf, oacc[mt], 0, 0, 0);
                }
            }
            __builtin_amdgcn_s_setprio(0);
        }
        cur ^= 1;
    }

    // ---- epilogue: normalize, store y[b,t,h,d] (bf16) ----
    const float inv = 1.0f / l_i;
    unsigned short* yrow = yb + (size_t)(b * T + qg) * 1024 + (h << 6);
    #pragma unroll
    for (int mt = 0; mt < 4; ++mt) {
        ushort4 yv;
        yv.x = f2bf(oacc[mt][0] * inv);
        yv.y = f2bf(oacc[mt][1] * inv);
        yv.z = f2bf(oacc[mt][2] * inv);
        yv.w = f2bf(oacc[mt][3] * inv);
        *(ushort4*)&yrow[mt * 16 + (quad << 2)] = yv;
    }
}

// ======================================================================
extern "C" void kernel_launch(void* const* d_in, const int* in_sizes, int n_in,
                              void* d_out, int out_size, void* d_ws, size_t ws_size,
                              hipStream_t stream)
{
    const float* x      = (const float*)d_in[0];
    const float* cosp   = (const float*)d_in[1];
    const float* sinp   = (const float*)d_in[2];
    const float* W_attn = (const float*)d_in[3];
    const float* b_attn = (const float*)d_in[4];
    const float* W_proj = (const float*)d_in[5];
    const float* b_proj = (const float*)d_in[6];
    float* out = (float*)d_out;

    const int C = 1024, H = 16;
    const int T  = in_sizes[1] / 64;     // cos: (T, 64)
    const int BT = in_sizes[0] / C;      // B*T
    const int B  = BT / T;

    unsigned short* qkvb = (unsigned short*)d_ws;              // BT*3072
    unsigned short* xb   = qkvb + (size_t)BT * 3072;           // BT*1024
    unsigned short* Wab  = xb   + (size_t)BT * 1024;           // 3072*1024
    unsigned short* Wpb  = Wab  + (size_t)3072 * 1024;         // 1024*1024
    unsigned short* yb   = Wpb  + (size_t)1024 * 1024;         // BT*1024
    unsigned short* vtb  = xb;   // vt aliases xb (x dead after gemm1)

    cast_bf16<<<dim3(BT * C / 1024), dim3(256), 0, stream>>>(x, xb, BT * C);
    transpose_cast_both<<<dim3(128, 32), dim3(256), 0, stream>>>(
        W_attn, Wab, W_proj, Wpb);

    gemm_bf16<true><<<dim3(3 * C / 128, BT / 128), dim3(256), 0, stream>>>(
        xb, Wab, b_attn, qkvb, BT, 3 * C, C);

    rmsnorm_rope<<<dim3(BT * 2), dim3(256), 0, stream>>>(
        qkvb, cosp, sinp, BT, T);

    v_transpose<<<dim3(B * H, T / 64), dim3(256), 0, stream>>>(qkvb, vtb, T);

    flash_attn_mfma<<<dim3(B * H, T / 128), dim3(512), 0, stream>>>(
        qkvb, vtb, yb, B, T);

    gemm_bf16_n64<<<dim3(C / 64, BT / 128), dim3(256), 0, stream>>>(
        yb, Wpb, b_proj, out, BT, C, C);
}

// Round 5
// 186.162 us; speedup vs baseline: 1.1413x; 1.0183x over previous
//
#include <hip/hip_runtime.h>
#include <math.h>

#define EPSV 1.1920929e-07f

typedef __attribute__((ext_vector_type(8))) short short8;
typedef __attribute__((ext_vector_type(4))) float f32x4;

__device__ __forceinline__ float bf2f(unsigned short u) {
    union { unsigned int i; float f; } c; c.i = ((unsigned int)u) << 16; return c.f;
}
__device__ __forceinline__ unsigned short f2bf(float f) {
    union { float f; unsigned int i; } c; c.f = f;
    unsigned int r = c.i + 0x7FFFu + ((c.i >> 16) & 1u);   // RNE
    return (unsigned short)(r >> 16);
}
// pack two f32 -> two bf16 (round-half-up) in one u32: low=a, high=b
__device__ __forceinline__ unsigned int pack_bf16_ru(float a, float b) {
    union { float f; unsigned int i; } ca, cb; ca.f = a; cb.f = b;
    return __builtin_amdgcn_perm(cb.i + 0x8000u, ca.i + 0x8000u, 0x07060302u);
}
// async global -> LDS, 16 B per lane (dest = wave-uniform base + lane*16)
__device__ __forceinline__ void async_lds16(const unsigned short* g, unsigned short* l) {
    __builtin_amdgcn_global_load_lds(
        (const __attribute__((address_space(1))) unsigned int*)g,
        (__attribute__((address_space(3))) unsigned int*)l, 16, 0, 0);
}

// ======================================================================
// MERGED prep: fp32->bf16 cast of x (blocks [0,castBlocks)) and
// transpose+cast of both weights (blocks [castBlocks, castBlocks+4096)).
// One launch instead of two.
// ======================================================================
__global__ __launch_bounds__(256) void prep_cast_transpose(
    const float* __restrict__ x, unsigned short* __restrict__ xb, int nCast,
    const float* __restrict__ Wa, unsigned short* __restrict__ Wat,
    const float* __restrict__ Wp, unsigned short* __restrict__ Wpt,
    int castBlocks)
{
    __shared__ float tile[32][33];
    const int bxg = blockIdx.x;
    if (bxg < castBlocks) {
        const int i = (bxg * 256 + threadIdx.x) * 4;
        if (i >= nCast) return;
        const float4 v = *(const float4*)&x[i];
        ushort4 o;
        o.x = f2bf(v.x); o.y = f2bf(v.y); o.z = f2bf(v.z); o.w = f2bf(v.w);
        *(ushort4*)&xb[i] = o;
        return;
    }
    const int r0 = bxg - castBlocks;
    int bx = r0 & 127;                      // 0..127
    const int by = r0 >> 7;                 // 0..31
    const float* W; unsigned short* Wt; int N;
    if (bx < 96) { W = Wa; Wt = Wat; N = 3072; }
    else         { W = Wp; Wt = Wpt; N = 1024; bx -= 96; }
    const int n0 = bx * 32, k0 = by * 32;
    const int r = threadIdx.x >> 3, c4 = (threadIdx.x & 7) * 4;
    const float4 v = *(const float4*)&W[(size_t)(k0 + r) * N + n0 + c4];
    tile[r][c4 + 0] = v.x; tile[r][c4 + 1] = v.y;
    tile[r][c4 + 2] = v.z; tile[r][c4 + 3] = v.w;
    __syncthreads();
    ushort4 o;
    o.x = f2bf(tile[c4 + 0][r]); o.y = f2bf(tile[c4 + 1][r]);
    o.z = f2bf(tile[c4 + 2][r]); o.w = f2bf(tile[c4 + 3][r]);
    *(ushort4*)&Wt[(size_t)(n0 + r) * 1024 + k0 + c4] = o;
}

// ======================================================================
// bf16 MFMA GEMM, m97 structure + BK=64. C = A @ Bt^T + bias.
// ======================================================================
template <bool OUT_BF16>
__global__ __launch_bounds__(256) void gemm_bf16(
    const unsigned short* __restrict__ A,
    const unsigned short* __restrict__ Bt,
    const float* __restrict__ bias,
    void* __restrict__ Cv,
    int M, int N, int K)
{
    __shared__ unsigned short As0[128][32], As1[128][32];
    __shared__ unsigned short Bs0[128][32], Bs1[128][32];
    const int t    = threadIdx.x;
    const int lane = t & 63;
    const int wv   = t >> 6;
    const int wrow = (wv >> 1) * 64;
    const int wcol = (wv & 1) * 64;
    const int m0 = blockIdx.y * 128;
    const int n0 = blockIdx.x * 128;
    const int col  = lane & 15;
    const int quad = lane >> 4;

    const int srow = (wv << 5) + (lane >> 2);     // wv*32 + 0..15
    const int scol = (lane & 3) << 3;             // 0,8,16,24
    const unsigned short* a00 = A  + (size_t)(m0 + srow) * K + scol;
    const unsigned short* a10 = a00 + (size_t)16 * K;
    const unsigned short* a01 = a00 + 32;
    const unsigned short* a11 = a10 + 32;
    const unsigned short* b00 = Bt + (size_t)(n0 + srow) * K + scol;
    const unsigned short* b10 = b00 + (size_t)16 * K;
    const unsigned short* b01 = b00 + 32;
    const unsigned short* b11 = b10 + 32;
    unsigned short* al0 = &As0[srow][scol];
    unsigned short* al1 = &As0[srow + 16][scol];
    unsigned short* al2 = &As1[srow][scol];
    unsigned short* al3 = &As1[srow + 16][scol];
    unsigned short* bl0 = &Bs0[srow][scol];
    unsigned short* bl1 = &Bs0[srow + 16][scol];
    unsigned short* bl2 = &Bs1[srow][scol];
    unsigned short* bl3 = &Bs1[srow + 16][scol];

    f32x4 acc[4][4];
    #pragma unroll
    for (int i = 0; i < 4; ++i)
        #pragma unroll
        for (int j = 0; j < 4; ++j)
            acc[i][j] = (f32x4){0.f, 0.f, 0.f, 0.f};

    for (int k0 = 0; k0 < K; k0 += 64) {
        async_lds16(a00, al0);
        async_lds16(a10, al1);
        async_lds16(a01, al2);
        async_lds16(a11, al3);
        async_lds16(b00, bl0);
        async_lds16(b10, bl1);
        async_lds16(b01, bl2);
        async_lds16(b11, bl3);
        a00 += 64; a10 += 64; a01 += 64; a11 += 64;
        b00 += 64; b10 += 64; b01 += 64; b11 += 64;
        __syncthreads();
        short8 af[2][4], bf[2][4];
        #pragma unroll
        for (int mt = 0; mt < 4; ++mt) {
            af[0][mt] = *(const short8*)&As0[wrow + mt * 16 + col][quad << 3];
            af[1][mt] = *(const short8*)&As1[wrow + mt * 16 + col][quad << 3];
        }
        #pragma unroll
        for (int nt = 0; nt < 4; ++nt) {
            bf[0][nt] = *(const short8*)&Bs0[wcol + nt * 16 + col][quad << 3];
            bf[1][nt] = *(const short8*)&Bs1[wcol + nt * 16 + col][quad << 3];
        }
        #pragma unroll
        for (int ks = 0; ks < 2; ++ks)
            #pragma unroll
            for (int mt = 0; mt < 4; ++mt)
                #pragma unroll
                for (int nt = 0; nt < 4; ++nt)
                    acc[mt][nt] = __builtin_amdgcn_mfma_f32_16x16x32_bf16(
                        af[ks][mt], bf[ks][nt], acc[mt][nt], 0, 0, 0);
        __syncthreads();
    }

    const int rowq = quad << 2;
    #pragma unroll
    for (int nt = 0; nt < 4; ++nt) {
        const int n = n0 + wcol + nt * 16 + col;
        const float bv = bias[n];
        #pragma unroll
        for (int mt = 0; mt < 4; ++mt) {
            #pragma unroll
            for (int r = 0; r < 4; ++r) {
                const int m = m0 + wrow + mt * 16 + rowq + r;
                const float v = acc[mt][nt][r] + bv;
                if (OUT_BF16)
                    ((unsigned short*)Cv)[(size_t)m * N + n] = f2bf(v);
                else
                    ((float*)Cv)[(size_t)m * N + n] = v;
            }
        }
    }
}

// ======================================================================
// bf16 MFMA GEMM, 128(M) x 64(N), BK=64 (skinny-N gemm2). fp32 out.
// ======================================================================
__global__ __launch_bounds__(256) void gemm_bf16_n64(
    const unsigned short* __restrict__ A,
    const unsigned short* __restrict__ Bt,
    const float* __restrict__ bias,
    float* __restrict__ C,
    int M, int N, int K)
{
    __shared__ unsigned short As0[128][32], As1[128][32];
    __shared__ unsigned short Bs0[64][32], Bs1[64][32];
    const int t    = threadIdx.x;
    const int lane = t & 63;
    const int wv   = t >> 6;
    const int wrow = wv << 5;
    const int m0 = blockIdx.y * 128;
    const int n0 = blockIdx.x * 64;
    const int col  = lane & 15;
    const int quad = lane >> 4;

    const int srow = (wv << 5) + (lane >> 2);
    const int scol = (lane & 3) << 3;
    const unsigned short* a00 = A  + (size_t)(m0 + srow) * K + scol;
    const unsigned short* a10 = a00 + (size_t)16 * K;
    const unsigned short* a01 = a00 + 32;
    const unsigned short* a11 = a10 + 32;
    const int bsrow = (wv << 4) + (lane >> 2);
    const unsigned short* b00 = Bt + (size_t)(n0 + bsrow) * K + scol;
    const unsigned short* b01 = b00 + 32;
    unsigned short* al0 = &As0[srow][scol];
    unsigned short* al1 = &As0[srow + 16][scol];
    unsigned short* al2 = &As1[srow][scol];
    unsigned short* al3 = &As1[srow + 16][scol];
    unsigned short* bl0 = &Bs0[bsrow][scol];
    unsigned short* bl1 = &Bs1[bsrow][scol];

    f32x4 acc[2][4];
    #pragma unroll
    for (int i = 0; i < 2; ++i)
        #pragma unroll
        for (int j = 0; j < 4; ++j)
            acc[i][j] = (f32x4){0.f, 0.f, 0.f, 0.f};

    for (int k0 = 0; k0 < K; k0 += 64) {
        async_lds16(a00, al0);
        async_lds16(a10, al1);
        async_lds16(a01, al2);
        async_lds16(a11, al3);
        async_lds16(b00, bl0);
        async_lds16(b01, bl1);
        a00 += 64; a10 += 64; a01 += 64; a11 += 64;
        b00 += 64; b01 += 64;
        __syncthreads();
        short8 af[2][2], bf[2][4];
        #pragma unroll
        for (int mt = 0; mt < 2; ++mt) {
            af[0][mt] = *(const short8*)&As0[wrow + mt * 16 + col][quad << 3];
            af[1][mt] = *(const short8*)&As1[wrow + mt * 16 + col][quad << 3];
        }
        #pragma unroll
        for (int nt = 0; nt < 4; ++nt) {
            bf[0][nt] = *(const short8*)&Bs0[nt * 16 + col][quad << 3];
            bf[1][nt] = *(const short8*)&Bs1[nt * 16 + col][quad << 3];
        }
        #pragma unroll
        for (int ks = 0; ks < 2; ++ks)
            #pragma unroll
            for (int mt = 0; mt < 2; ++mt)
                #pragma unroll
                for (int nt = 0; nt < 4; ++nt)
                    acc[mt][nt] = __builtin_amdgcn_mfma_f32_16x16x32_bf16(
                        af[ks][mt], bf[ks][nt], acc[mt][nt], 0, 0, 0);
        __syncthreads();
    }

    const int rowq = quad << 2;
    #pragma unroll
    for (int nt = 0; nt < 4; ++nt) {
        const int n = n0 + nt * 16 + col;
        const float bv = bias[n];
        #pragma unroll
        for (int mt = 0; mt < 2; ++mt) {
            #pragma unroll
            for (int r = 0; r < 4; ++r) {
                const int m = m0 + wrow + mt * 16 + rowq + r;
                C[(size_t)m * N + n] = acc[mt][nt][r] + bv;
            }
        }
    }
}

// ======================================================================
// MERGED: RMSNorm+rotary on q/k (blocks [0, BT*2)) and V transpose
// (blocks [BT*2, BT*2 + B*H*T/64)). Disjoint qkv slices -> no ordering
// hazard. One launch instead of two.
// ======================================================================
__global__ __launch_bounds__(256) void rmsrope_vt(
    unsigned short* __restrict__ qkv, const float* __restrict__ cosp,
    const float* __restrict__ sinp, unsigned short* __restrict__ vt,
    int BT, int T)
{
    __shared__ unsigned short tile[64][72];
    const int nrms = BT * 2;
    const int bxg = (int)blockIdx.x;
    if (bxg < nrms) {
        const int wid  = (bxg << 2) + (threadIdx.x >> 6);
        const int lane = threadIdx.x & 63;
        const int hq = wid & 3;
        const int w  = (wid >> 2) & 1;
        const int bt = wid >> 3;
        if (bt >= BT) return;
        const int h  = (hq << 2) + (lane >> 4);
        const int d4 = (lane & 15) << 2;
        const int tpos = bt % T;
        const size_t idx = (size_t)bt * 3072 + (w << 10) + (h << 6) + d4;

        const ushort4 u = *(const ushort4*)&qkv[idx];
        const float x0 = bf2f(u.x), x1 = bf2f(u.y), x2 = bf2f(u.z), x3 = bf2f(u.w);
        float ss = x0 * x0 + x1 * x1 + x2 * x2 + x3 * x3;
        ss += __shfl_xor(ss, 1, 64);
        ss += __shfl_xor(ss, 2, 64);
        ss += __shfl_xor(ss, 4, 64);
        ss += __shfl_xor(ss, 8, 64);
        const float rn = rsqrtf(ss * (1.0f / 64.0f) + EPSV);
        const float xn0 = x0 * rn, xn1 = x1 * rn, xn2 = x2 * rn, xn3 = x3 * rn;
        const float p0 = __shfl_xor(xn0, 8, 64);
        const float p1 = __shfl_xor(xn1, 8, 64);
        const float p2 = __shfl_xor(xn2, 8, 64);
        const float p3 = __shfl_xor(xn3, 8, 64);
        const float sgn = (d4 < 32) ? -1.0f : 1.0f;
        const float4 c = *(const float4*)&cosp[tpos * 64 + d4];
        const float4 s = *(const float4*)&sinp[tpos * 64 + d4];
        const float scale = (w == 0) ? 0.18033688011112042f : 1.0f;  // log2e/8
        ushort4 o;
        o.x = f2bf(fmaf(xn0, c.x, sgn * p0 * s.x) * scale);
        o.y = f2bf(fmaf(xn1, c.y, sgn * p1 * s.y) * scale);
        o.z = f2bf(fmaf(xn2, c.z, sgn * p2 * s.z) * scale);
        o.w = f2bf(fmaf(xn3, c.w, sgn * p3 * s.w) * scale);
        *(ushort4*)&qkv[idx] = o;
        return;
    }
    // ---- V transpose part ----
    const int r0 = bxg - nrms;
    const int tdiv = T >> 6;
    const int bh = r0 / tdiv;
    const int ty = r0 - bh * tdiv;
    const int b  = bh >> 4, h = bh & 15;
    const int t0 = ty << 6;
    const int t  = threadIdx.x;
    const unsigned short* vbase = qkv + (size_t)b * T * 3072 + 2048 + (h << 6);

    #pragma unroll
    for (int i = 0; i < 2; ++i) {
        const int c = t + (i << 8);
        const int r = c >> 3, c8 = (c & 7) << 3;
        const short8 v = *(const short8*)&vbase[(size_t)(t0 + r) * 3072 + c8];
        #pragma unroll
        for (int j = 0; j < 8; ++j)
            tile[c8 + j][r] = (unsigned short)v[j];
    }
    __syncthreads();
    #pragma unroll
    for (int i = 0; i < 2; ++i) {
        const int c = t + (i << 8);
        const int d = c >> 3, c8 = (c & 7) << 3;
        const short8 o = *(const short8*)&tile[d][c8];
        *(short8*)&vt[((size_t)bh * 64 + d) * T + t0 + c8] = o;
    }
}

// ======================================================================
// MFMA flash attention, FIXED-MAX softmax, q-tile 128, 8 waves x 16 q
// (R4 structure -- verified). R5 tweak: l_i cross-quad reduction
// (2 ds_bpermute on the LDS pipe per wave-iter) DEFERRED to epilogue;
// per-lane partials accumulate in-loop (sum is order-independent).
// ======================================================================
__global__ __launch_bounds__(512, 4) void flash_attn_mfma(
    const unsigned short* __restrict__ qkv,
    const unsigned short* __restrict__ vt,
    unsigned short* __restrict__ yb,
    int B, int T)
{
    const int bh = blockIdx.x;
    const int b  = bh >> 4, h = bh & 15;
    const int ny = (int)gridDim.y;
    const int y  = (int)blockIdx.y;
    const int hny = (ny + 1) >> 1;
    const int jq = (y < hny) ? (ny - 1 - y) : (y - hny);   // balanced pairing
    const int q0 = jq << 7;
    const int t  = threadIdx.x;
    const int lane = t & 63;
    const int w    = t >> 6;       // 0..7, each owns 16 q-rows
    const int col  = lane & 15;
    const int quad = lane >> 4;

    // [0,8192): Kb[2][64][64]  [8192,16384): Vb[2][64][64]
    // [16384,25600): Ps[8][16][72]          (total 51200 B)
    __shared__ __align__(16) unsigned short smem[25600];
    unsigned short* Kb = smem;
    unsigned short* Vb = smem + 8192;
    unsigned short* Ps = smem + 16384;

    const unsigned short* qb  = qkv + (size_t)b * T * 3072 + (h << 6);
    const unsigned short* kb  = qb + 1024;
    const unsigned short* vtb = vt + (size_t)bh * 64 * T;

    const int qw = q0 + (w << 4);        // wave's first q row (16 rows)
    const int qg = qw + col;             // lane's q row

    short8 qf[2];
    {
        const unsigned short* qrow = qb + (size_t)qg * 3072 + (quad << 3);
        qf[0] = *(const short8*)&qrow[0];
        qf[1] = *(const short8*)&qrow[32];
    }

    f32x4 oacc[4];
    #pragma unroll
    for (int i = 0; i < 4; ++i) oacc[i] = (f32x4){0.f, 0.f, 0.f, 0.f};
    float l_i = 0.f;   // per-lane partial; reduced across quads in epilogue

    // ---- async staging: 512 threads, 1 K + 1 V load each ----
    const int sr = t >> 3;                         // row 0..63
    const int sg = (((t & 7) ^ (sr & 7)) << 3);    // swizzled chunk * 8 elems
    const unsigned short* kp = kb  + (size_t)sr * 3072 + sg;
    const unsigned short* vp = vtb + (size_t)sr * T + sg;

    // prologue: tile 0 -> buffer 0
    async_lds16(kp, Kb + (t << 3));
    async_lds16(vp, Vb + (t << 3));
    kp += (size_t)64 * 3072; vp += 64;

    // per-lane swizzled chunk element-offsets for fragment reads
    const int cs0 = ((quad ^ (col & 7)) << 3);
    const int cs1 = (((4 + quad) ^ (col & 7)) << 3);

    const int last_kt = (q0 + 127) >> 6;
    int cur = 0;
    for (int kt = 0; kt <= last_kt; ++kt) {
        const int k0 = kt << 6;
        __syncthreads();   // drains async -> buf[cur] ready; prev compute done
        if (kt < last_kt) {
            async_lds16(kp, Kb + ((cur ^ 1) << 12) + (t << 3));
            async_lds16(vp, Vb + ((cur ^ 1) << 12) + (t << 3));
            kp += (size_t)64 * 3072; vp += 64;
        }

        // wave-uniform skip of fully-masked tiles
        if (k0 <= qw + 15) {
            const unsigned short* Kc = Kb + (cur << 12);
            const unsigned short* Vc = Vb + (cur << 12);

            // ---- S^T = K @ Q^T ----
            f32x4 st[4];
            #pragma unroll
            for (int i = 0; i < 4; ++i) st[i] = (f32x4){0.f, 0.f, 0.f, 0.f};
            __builtin_amdgcn_s_setprio(1);
            #pragma unroll
            for (int ks = 0; ks < 2; ++ks)
                #pragma unroll
                for (int mt = 0; mt < 4; ++mt) {
                    const short8 kf = *(const short8*)&Kc[(mt * 16 + col) * 64 + (ks ? cs1 : cs0)];
                    st[mt] = __builtin_amdgcn_mfma_f32_16x16x32_bf16(kf, qf[ks], st[mt], 0, 0, 0);
                }
            __builtin_amdgcn_s_setprio(0);

            // ---- fixed-max softmax: p = exp2(s), mask via exp2(-inf)=0 ----
            const bool diag = (k0 + 63 > qw);
            unsigned short* pw = Ps + ((w << 4) + col) * 72;
            float rs = 0.f;
            #pragma unroll
            for (int mt = 0; mt < 4; ++mt) {
                float x0 = st[mt][0], x1 = st[mt][1];
                float x2 = st[mt][2], x3 = st[mt][3];
                if (diag) {
                    const int sbase = k0 + mt * 16 + (quad << 2);
                    if (sbase + 0 > qg) x0 = -INFINITY;
                    if (sbase + 1 > qg) x1 = -INFINITY;
                    if (sbase + 2 > qg) x2 = -INFINITY;
                    if (sbase + 3 > qg) x3 = -INFINITY;
                }
                const float p0 = __builtin_amdgcn_exp2f(x0);
                const float p1 = __builtin_amdgcn_exp2f(x1);
                const float p2 = __builtin_amdgcn_exp2f(x2);
                const float p3 = __builtin_amdgcn_exp2f(x3);
                rs += (p0 + p1) + (p2 + p3);
                uint2 pk;
                pk.x = pack_bf16_ru(p0, p1);
                pk.y = pack_bf16_ru(p2, p3);
                *(uint2*)&pw[mt * 16 + (quad << 2)] = pk;
            }
            l_i += rs;   // per-lane partial (this lane's quad-slots only)

            // ---- O^T += V^T @ P^T ----
            __builtin_amdgcn_s_setprio(1);
            #pragma unroll
            for (int ks = 0; ks < 2; ++ks) {
                const short8 pf = *(const short8*)&Ps[((w << 4) + col) * 72 + ks * 32 + (quad << 3)];
                #pragma unroll
                for (int mt = 0; mt < 4; ++mt) {
                    const short8 vf = *(const short8*)&Vc[(mt * 16 + col) * 64 + (ks ? cs1 : cs0)];
                    oacc[mt] = __builtin_amdgcn_mfma_f32_16x16x32_bf16(vf, pf, oacc[mt], 0, 0, 0);
                }
            }
            __builtin_amdgcn_s_setprio(0);
        }
        cur ^= 1;
    }

    // ---- epilogue: reduce l across quads, normalize, store ----
    l_i += __shfl_xor(l_i, 16, 64);
    l_i += __shfl_xor(l_i, 32, 64);
    const float inv = 1.0f / l_i;
    unsigned short* yrow = yb + (size_t)(b * T + qg) * 1024 + (h << 6);
    #pragma unroll
    for (int mt = 0; mt < 4; ++mt) {
        ushort4 yv;
        yv.x = f2bf(oacc[mt][0] * inv);
        yv.y = f2bf(oacc[mt][1] * inv);
        yv.z = f2bf(oacc[mt][2] * inv);
        yv.w = f2bf(oacc[mt][3] * inv);
        *(ushort4*)&yrow[mt * 16 + (quad << 2)] = yv;
    }
}

// ======================================================================
extern "C" void kernel_launch(void* const* d_in, const int* in_sizes, int n_in,
                              void* d_out, int out_size, void* d_ws, size_t ws_size,
                              hipStream_t stream)
{
    const float* x      = (const float*)d_in[0];
    const float* cosp   = (const float*)d_in[1];
    const float* sinp   = (const float*)d_in[2];
    const float* W_attn = (const float*)d_in[3];
    const float* b_attn = (const float*)d_in[4];
    const float* W_proj = (const float*)d_in[5];
    const float* b_proj = (const float*)d_in[6];
    float* out = (float*)d_out;

    const int C = 1024, H = 16;
    const int T  = in_sizes[1] / 64;     // cos: (T, 64)
    const int BT = in_sizes[0] / C;      // B*T
    const int B  = BT / T;

    unsigned short* qkvb = (unsigned short*)d_ws;              // BT*3072
    unsigned short* xb   = qkvb + (size_t)BT * 3072;           // BT*1024
    unsigned short* Wab  = xb   + (size_t)BT * 1024;           // 3072*1024
    unsigned short* Wpb  = Wab  + (size_t)3072 * 1024;         // 1024*1024
    unsigned short* yb   = Wpb  + (size_t)1024 * 1024;         // BT*1024
    unsigned short* vtb  = xb;   // vt aliases xb (x dead after gemm1)

    const int castBlocks = BT * C / 1024;
    prep_cast_transpose<<<dim3(castBlocks + 4096), dim3(256), 0, stream>>>(
        x, xb, BT * C, W_attn, Wab, W_proj, Wpb, castBlocks);

    gemm_bf16<true><<<dim3(3 * C / 128, BT / 128), dim3(256), 0, stream>>>(
        xb, Wab, b_attn, qkvb, BT, 3 * C, C);

    rmsrope_vt<<<dim3(BT * 2 + B * H * (T >> 6)), dim3(256), 0, stream>>>(
        qkvb, cosp, sinp, vtb, BT, T);

    flash_attn_mfma<<<dim3(B * H, T / 128), dim3(512), 0, stream>>>(
        qkvb, vtb, yb, B, T);

    gemm_bf16_n64<<<dim3(C / 64, BT / 128), dim3(256), 0, stream>>>(
        yb, Wpb, b_proj, out, BT, C, C);
}

// Round 7
// 176.904 us; speedup vs baseline: 1.2010x; 1.0523x over previous
//
#include <hip/hip_runtime.h>
#include <math.h>

#define EPSV 1.1920929e-07f

typedef __attribute__((ext_vector_type(8))) short short8;
typedef __attribute__((ext_vector_type(4))) float f32x4;

__device__ __forceinline__ float bf2f(unsigned short u) {
    union { unsigned int i; float f; } c; c.i = ((unsigned int)u) << 16; return c.f;
}
__device__ __forceinline__ unsigned short f2bf(float f) {
    union { float f; unsigned int i; } c; c.f = f;
    unsigned int r = c.i + 0x7FFFu + ((c.i >> 16) & 1u);   // RNE
    return (unsigned short)(r >> 16);
}
// pack two f32 -> two bf16 (round-half-up) in one u32: low=a, high=b
__device__ __forceinline__ unsigned int pack_bf16_ru(float a, float b) {
    union { float f; unsigned int i; } ca, cb; ca.f = a; cb.f = b;
    return __builtin_amdgcn_perm(cb.i + 0x8000u, ca.i + 0x8000u, 0x07060302u);
}
// async global -> LDS, 16 B per lane (dest = wave-uniform base + lane*16)
__device__ __forceinline__ void async_lds16(const unsigned short* g, unsigned short* l) {
    __builtin_amdgcn_global_load_lds(
        (const __attribute__((address_space(1))) unsigned int*)g,
        (__attribute__((address_space(3))) unsigned int*)l, 16, 0, 0);
}

// ======================================================================
// MERGED prep: fp32->bf16 cast of x | transpose+cast of both weights |
// packed cos/sin table cs[T][32] (float2; cos[d]=cos[d%32] by concat).
// ======================================================================
__global__ __launch_bounds__(256) void prep_cast_transpose(
    const float* __restrict__ x, unsigned short* __restrict__ xb, int nCast,
    const float* __restrict__ Wa, unsigned short* __restrict__ Wat,
    const float* __restrict__ Wp, unsigned short* __restrict__ Wpt,
    const float* __restrict__ cosp, const float* __restrict__ sinp,
    float2* __restrict__ cs, int castBlocks)
{
    __shared__ float tile[32][33];
    const int bxg = blockIdx.x;
    if (bxg < castBlocks) {
        const int i = (bxg * 256 + threadIdx.x) * 4;
        if (i >= nCast) return;
        const float4 v = *(const float4*)&x[i];
        ushort4 o;
        o.x = f2bf(v.x); o.y = f2bf(v.y); o.z = f2bf(v.z); o.w = f2bf(v.w);
        *(ushort4*)&xb[i] = o;
        return;
    }
    if (bxg >= castBlocks + 4096) {   // cs table part
        const int i = (bxg - castBlocks - 4096) * 256 + threadIdx.x;
        const int tp = i >> 5, dp = i & 31;
        cs[i] = make_float2(cosp[tp * 64 + dp], sinp[tp * 64 + dp]);
        return;
    }
    const int r0 = bxg - castBlocks;
    int bx = r0 & 127;                      // 0..127
    const int by = r0 >> 7;                 // 0..31
    const float* W; unsigned short* Wt; int N;
    if (bx < 96) { W = Wa; Wt = Wat; N = 3072; }
    else         { W = Wp; Wt = Wpt; N = 1024; bx -= 96; }
    const int n0 = bx * 32, k0 = by * 32;
    const int r = threadIdx.x >> 3, c4 = (threadIdx.x & 7) * 4;
    const float4 v = *(const float4*)&W[(size_t)(k0 + r) * N + n0 + c4];
    tile[r][c4 + 0] = v.x; tile[r][c4 + 1] = v.y;
    tile[r][c4 + 2] = v.z; tile[r][c4 + 3] = v.w;
    __syncthreads();
    ushort4 o;
    o.x = f2bf(tile[c4 + 0][r]); o.y = f2bf(tile[c4 + 1][r]);
    o.z = f2bf(tile[c4 + 2][r]); o.w = f2bf(tile[c4 + 3][r]);
    *(ushort4*)&Wt[(size_t)(n0 + r) * 1024 + k0 + c4] = o;
}

// ======================================================================
// FUSED qkv GEMM (N=3072): C = A @ Bt^T + bias, then IN-EPILOGUE:
//  * q/k n-tiles (n0<2048): RMSNorm over the head's 64 outputs (f32,
//    cross-lane shfl over the 16-col group; nt covers the other 48) +
//    RoPE (d<->d+32 is nt<->nt+2, in-lane; cs[T][32] float2 table) +
//    q pre-scale log2e/8; store bf16 to qkv.
//  * v n-tiles (n0>=2048): bias only, bounce through a [128][136] LDS
//    tile (unions the dead staging buffers) and store TRANSPOSED to
//    vt[bh*64+d][T] with coalesced 16B rows.
// Replaces the separate rmsnorm_rope + v_transpose kernels (one full
// qkv memory round-trip + a launch gap).
// ======================================================================
__global__ __launch_bounds__(256) void gemm_qkv(
    const unsigned short* __restrict__ A,
    const unsigned short* __restrict__ Bt,
    const float* __restrict__ bias,
    unsigned short* __restrict__ qkv,
    unsigned short* __restrict__ vt,
    const float2* __restrict__ cs,
    int M, int K, int T)
{
    const int N = 3072;
    // union: staging As0/As1/Bs0/Bs1 (4 x [128][32]) | vtile [128][136]
    __shared__ __align__(16) unsigned short smem[17408];
    unsigned short* As0 = smem;
    unsigned short* As1 = smem + 4096;
    unsigned short* Bs0 = smem + 8192;
    unsigned short* Bs1 = smem + 12288;

    const int t    = threadIdx.x;
    const int lane = t & 63;
    const int wv   = t >> 6;
    const int wrow = (wv >> 1) * 64;
    const int wcol = (wv & 1) * 64;
    const int m0 = blockIdx.y * 128;
    const int n0 = blockIdx.x * 128;
    const int col  = lane & 15;
    const int quad = lane >> 4;

    const int srow = (wv << 5) + (lane >> 2);     // wv*32 + 0..15
    const int scol = (lane & 3) << 3;             // 0,8,16,24
    const unsigned short* a00 = A  + (size_t)(m0 + srow) * K + scol;
    const unsigned short* a10 = a00 + (size_t)16 * K;
    const unsigned short* a01 = a00 + 32;
    const unsigned short* a11 = a10 + 32;
    const unsigned short* b00 = Bt + (size_t)(n0 + srow) * K + scol;
    const unsigned short* b10 = b00 + (size_t)16 * K;
    const unsigned short* b01 = b00 + 32;
    const unsigned short* b11 = b10 + 32;
    unsigned short* al0 = &As0[srow * 32 + scol];
    unsigned short* al1 = &As0[(srow + 16) * 32 + scol];
    unsigned short* al2 = &As1[srow * 32 + scol];
    unsigned short* al3 = &As1[(srow + 16) * 32 + scol];
    unsigned short* bl0 = &Bs0[srow * 32 + scol];
    unsigned short* bl1 = &Bs0[(srow + 16) * 32 + scol];
    unsigned short* bl2 = &Bs1[srow * 32 + scol];
    unsigned short* bl3 = &Bs1[(srow + 16) * 32 + scol];

    f32x4 acc[4][4];
    #pragma unroll
    for (int i = 0; i < 4; ++i)
        #pragma unroll
        for (int j = 0; j < 4; ++j)
            acc[i][j] = (f32x4){0.f, 0.f, 0.f, 0.f};

    for (int k0 = 0; k0 < K; k0 += 64) {
        async_lds16(a00, al0);
        async_lds16(a10, al1);
        async_lds16(a01, al2);
        async_lds16(a11, al3);
        async_lds16(b00, bl0);
        async_lds16(b10, bl1);
        async_lds16(b01, bl2);
        async_lds16(b11, bl3);
        a00 += 64; a10 += 64; a01 += 64; a11 += 64;
        b00 += 64; b10 += 64; b01 += 64; b11 += 64;
        __syncthreads();
        short8 af[2][4], bf[2][4];
        #pragma unroll
        for (int mt = 0; mt < 4; ++mt) {
            af[0][mt] = *(const short8*)&As0[(wrow + mt * 16 + col) * 32 + (quad << 3)];
            af[1][mt] = *(const short8*)&As1[(wrow + mt * 16 + col) * 32 + (quad << 3)];
        }
        #pragma unroll
        for (int nt = 0; nt < 4; ++nt) {
            bf[0][nt] = *(const short8*)&Bs0[(wcol + nt * 16 + col) * 32 + (quad << 3)];
            bf[1][nt] = *(const short8*)&Bs1[(wcol + nt * 16 + col) * 32 + (quad << 3)];
        }
        #pragma unroll
        for (int ks = 0; ks < 2; ++ks)
            #pragma unroll
            for (int mt = 0; mt < 4; ++mt)
                #pragma unroll
                for (int nt = 0; nt < 4; ++nt)
                    acc[mt][nt] = __builtin_amdgcn_mfma_f32_16x16x32_bf16(
                        af[ks][mt], bf[ks][nt], acc[mt][nt], 0, 0, 0);
        __syncthreads();
    }

    // ---- bias (all paths) ----
    #pragma unroll
    for (int nt = 0; nt < 4; ++nt) {
        const float bv = bias[n0 + wcol + nt * 16 + col];
        #pragma unroll
        for (int mt = 0; mt < 4; ++mt)
            #pragma unroll
            for (int r = 0; r < 4; ++r)
                acc[mt][nt][r] += bv;
    }

    const int b     = m0 / T;          // batch (tile never spans batches)
    const int tpos0 = m0 - b * T;

    if (n0 < 2048) {
        // ---- q/k: RMSNorm + RoPE, store bf16 to qkv ----
        const int n_lin = n0 + wcol;
        const float scale = (n_lin < 1024) ? 0.18033688011112042f : 1.0f; // log2e/8 for q
        #pragma unroll
        for (int mt = 0; mt < 4; ++mt) {
            #pragma unroll
            for (int r = 0; r < 4; ++r) {
                float ss = acc[mt][0][r] * acc[mt][0][r]
                         + acc[mt][1][r] * acc[mt][1][r]
                         + acc[mt][2][r] * acc[mt][2][r]
                         + acc[mt][3][r] * acc[mt][3][r];
                ss += __shfl_xor(ss, 1, 64);
                ss += __shfl_xor(ss, 2, 64);
                ss += __shfl_xor(ss, 4, 64);
                ss += __shfl_xor(ss, 8, 64);
                const float rn = rsqrtf(ss * (1.0f / 64.0f) + EPSV) * scale;
                const int tpos = tpos0 + wrow + mt * 16 + (quad << 2) + r;
                const float2 c0 = cs[tpos * 32 + col];
                const float2 c1 = cs[tpos * 32 + 16 + col];
                const float o0 = (acc[mt][0][r] * c0.x - acc[mt][2][r] * c0.y) * rn;
                const float o1 = (acc[mt][1][r] * c1.x - acc[mt][3][r] * c1.y) * rn;
                const float o2 = (acc[mt][2][r] * c0.x + acc[mt][0][r] * c0.y) * rn;
                const float o3 = (acc[mt][3][r] * c1.x + acc[mt][1][r] * c1.y) * rn;
                const int m = m0 + wrow + mt * 16 + (quad << 2) + r;
                unsigned short* qr = qkv + (size_t)m * N + n_lin + col;
                qr[0]  = f2bf(o0);
                qr[16] = f2bf(o1);
                qr[32] = f2bf(o2);
                qr[48] = f2bf(o3);
            }
        }
    } else {
        // ---- v: transpose via LDS bounce, store to vt[bh*64+d][T] ----
        unsigned short (*vtile)[136] = (unsigned short(*)[136])smem;
        __syncthreads();   // staging buffers dead; safe to repurpose
        #pragma unroll
        for (int nt = 0; nt < 4; ++nt)
            #pragma unroll
            for (int mt = 0; mt < 4; ++mt)
                #pragma unroll
                for (int r = 0; r < 4; ++r)
                    vtile[wcol + nt * 16 + col][wrow + mt * 16 + (quad << 2) + r]
                        = f2bf(acc[mt][nt][r]);
        __syncthreads();
        const int td = t >> 4;          // 0..15
        const int mloc = (t & 15) << 3; // 0,8,..,120
        const int h2base = (n0 - 2048) >> 6;
        #pragma unroll
        for (int i = 0; i < 8; ++i) {
            const int dl = td + i * 16;
            const short8 o = *(const short8*)&vtile[dl][mloc];
            const int h2 = h2base + (dl >> 6);
            const size_t row = ((size_t)(b * 16 + h2) << 6) + (dl & 63);
            *(short8*)&vt[row * T + tpos0 + mloc] = o;
        }
    }
}

// ======================================================================
// bf16 MFMA GEMM, 128(M) x 64(N), BK=64 (skinny-N gemm2). fp32 out.
// ======================================================================
__global__ __launch_bounds__(256) void gemm_bf16_n64(
    const unsigned short* __restrict__ A,
    const unsigned short* __restrict__ Bt,
    const float* __restrict__ bias,
    float* __restrict__ C,
    int M, int N, int K)
{
    __shared__ unsigned short As0[128][32], As1[128][32];
    __shared__ unsigned short Bs0[64][32], Bs1[64][32];
    const int t    = threadIdx.x;
    const int lane = t & 63;
    const int wv   = t >> 6;
    const int wrow = wv << 5;
    const int m0 = blockIdx.y * 128;
    const int n0 = blockIdx.x * 64;
    const int col  = lane & 15;
    const int quad = lane >> 4;

    const int srow = (wv << 5) + (lane >> 2);
    const int scol = (lane & 3) << 3;
    const unsigned short* a00 = A  + (size_t)(m0 + srow) * K + scol;
    const unsigned short* a10 = a00 + (size_t)16 * K;
    const unsigned short* a01 = a00 + 32;
    const unsigned short* a11 = a10 + 32;
    const int bsrow = (wv << 4) + (lane >> 2);
    const unsigned short* b00 = Bt + (size_t)(n0 + bsrow) * K + scol;
    const unsigned short* b01 = b00 + 32;
    unsigned short* al0 = &As0[srow][scol];
    unsigned short* al1 = &As0[srow + 16][scol];
    unsigned short* al2 = &As1[srow][scol];
    unsigned short* al3 = &As1[srow + 16][scol];
    unsigned short* bl0 = &Bs0[bsrow][scol];
    unsigned short* bl1 = &Bs1[bsrow][scol];

    f32x4 acc[2][4];
    #pragma unroll
    for (int i = 0; i < 2; ++i)
        #pragma unroll
        for (int j = 0; j < 4; ++j)
            acc[i][j] = (f32x4){0.f, 0.f, 0.f, 0.f};

    for (int k0 = 0; k0 < K; k0 += 64) {
        async_lds16(a00, al0);
        async_lds16(a10, al1);
        async_lds16(a01, al2);
        async_lds16(a11, al3);
        async_lds16(b00, bl0);
        async_lds16(b01, bl1);
        a00 += 64; a10 += 64; a01 += 64; a11 += 64;
        b00 += 64; b01 += 64;
        __syncthreads();
        short8 af[2][2], bf[2][4];
        #pragma unroll
        for (int mt = 0; mt < 2; ++mt) {
            af[0][mt] = *(const short8*)&As0[wrow + mt * 16 + col][quad << 3];
            af[1][mt] = *(const short8*)&As1[wrow + mt * 16 + col][quad << 3];
        }
        #pragma unroll
        for (int nt = 0; nt < 4; ++nt) {
            bf[0][nt] = *(const short8*)&Bs0[nt * 16 + col][quad << 3];
            bf[1][nt] = *(const short8*)&Bs1[nt * 16 + col][quad << 3];
        }
        #pragma unroll
        for (int ks = 0; ks < 2; ++ks)
            #pragma unroll
            for (int mt = 0; mt < 2; ++mt)
                #pragma unroll
                for (int nt = 0; nt < 4; ++nt)
                    acc[mt][nt] = __builtin_amdgcn_mfma_f32_16x16x32_bf16(
                        af[ks][mt], bf[ks][nt], acc[mt][nt], 0, 0, 0);
        __syncthreads();
    }

    const int rowq = quad << 2;
    #pragma unroll
    for (int nt = 0; nt < 4; ++nt) {
        const int n = n0 + nt * 16 + col;
        const float bv = bias[n];
        #pragma unroll
        for (int mt = 0; mt < 2; ++mt) {
            #pragma unroll
            for (int r = 0; r < 4; ++r) {
                const int m = m0 + wrow + mt * 16 + rowq + r;
                C[(size_t)m * N + n] = acc[mt][nt][r] + bv;
            }
        }
    }
}

// ======================================================================
// MFMA flash attention, FIXED-MAX softmax, q-tile 128, 8 waves x 16 q
// (R4/R5 verified structure).
// ======================================================================
__global__ __launch_bounds__(512, 4) void flash_attn_mfma(
    const unsigned short* __restrict__ qkv,
    const unsigned short* __restrict__ vt,
    unsigned short* __restrict__ yb,
    int B, int T)
{
    const int bh = blockIdx.x;
    const int b  = bh >> 4, h = bh & 15;
    const int ny = (int)gridDim.y;
    const int y  = (int)blockIdx.y;
    const int hny = (ny + 1) >> 1;
    const int jq = (y < hny) ? (ny - 1 - y) : (y - hny);   // balanced pairing
    const int q0 = jq << 7;
    const int t  = threadIdx.x;
    const int lane = t & 63;
    const int w    = t >> 6;       // 0..7, each owns 16 q-rows
    const int col  = lane & 15;
    const int quad = lane >> 4;

    __shared__ __align__(16) unsigned short smem[25600];
    unsigned short* Kb = smem;
    unsigned short* Vb = smem + 8192;
    unsigned short* Ps = smem + 16384;

    const unsigned short* qb  = qkv + (size_t)b * T * 3072 + (h << 6);
    const unsigned short* kb  = qb + 1024;
    const unsigned short* vtb = vt + (size_t)bh * 64 * T;

    const int qw = q0 + (w << 4);        // wave's first q row (16 rows)
    const int qg = qw + col;             // lane's q row

    short8 qf[2];
    {
        const unsigned short* qrow = qb + (size_t)qg * 3072 + (quad << 3);
        qf[0] = *(const short8*)&qrow[0];
        qf[1] = *(const short8*)&qrow[32];
    }

    f32x4 oacc[4];
    #pragma unroll
    for (int i = 0; i < 4; ++i) oacc[i] = (f32x4){0.f, 0.f, 0.f, 0.f};
    float l_i = 0.f;   // per-lane partial; reduced across quads in epilogue

    const int sr = t >> 3;                         // row 0..63
    const int sg = (((t & 7) ^ (sr & 7)) << 3);    // swizzled chunk * 8 elems
    const unsigned short* kp = kb  + (size_t)sr * 3072 + sg;
    const unsigned short* vp = vtb + (size_t)sr * T + sg;

    async_lds16(kp, Kb + (t << 3));
    async_lds16(vp, Vb + (t << 3));
    kp += (size_t)64 * 3072; vp += 64;

    const int cs0 = ((quad ^ (col & 7)) << 3);
    const int cs1 = (((4 + quad) ^ (col & 7)) << 3);

    const int last_kt = (q0 + 127) >> 6;
    int cur = 0;
    for (int kt = 0; kt <= last_kt; ++kt) {
        const int k0 = kt << 6;
        __syncthreads();   // drains async -> buf[cur] ready; prev compute done
        if (kt < last_kt) {
            async_lds16(kp, Kb + ((cur ^ 1) << 12) + (t << 3));
            async_lds16(vp, Vb + ((cur ^ 1) << 12) + (t << 3));
            kp += (size_t)64 * 3072; vp += 64;
        }

        if (k0 <= qw + 15) {
            const unsigned short* Kc = Kb + (cur << 12);
            const unsigned short* Vc = Vb + (cur << 12);

            // ---- S^T = K @ Q^T ----
            f32x4 st[4];
            #pragma unroll
            for (int i = 0; i < 4; ++i) st[i] = (f32x4){0.f, 0.f, 0.f, 0.f};
            __builtin_amdgcn_s_setprio(1);
            #pragma unroll
            for (int ks = 0; ks < 2; ++ks)
                #pragma unroll
                for (int mt = 0; mt < 4; ++mt) {
                    const short8 kf = *(const short8*)&Kc[(mt * 16 + col) * 64 + (ks ? cs1 : cs0)];
                    st[mt] = __builtin_amdgcn_mfma_f32_16x16x32_bf16(kf, qf[ks], st[mt], 0, 0, 0);
                }
            __builtin_amdgcn_s_setprio(0);

            // ---- fixed-max softmax: p = exp2(s), mask via exp2(-inf)=0 ----
            const bool diag = (k0 + 63 > qw);
            unsigned short* pw = Ps + ((w << 4) + col) * 72;
            float rs = 0.f;
            #pragma unroll
            for (int mt = 0; mt < 4; ++mt) {
                float x0 = st[mt][0], x1 = st[mt][1];
                float x2 = st[mt][2], x3 = st[mt][3];
                if (diag) {
                    const int sbase = k0 + mt * 16 + (quad << 2);
                    if (sbase + 0 > qg) x0 = -INFINITY;
                    if (sbase + 1 > qg) x1 = -INFINITY;
                    if (sbase + 2 > qg) x2 = -INFINITY;
                    if (sbase + 3 > qg) x3 = -INFINITY;
                }
                const float p0 = __builtin_amdgcn_exp2f(x0);
                const float p1 = __builtin_amdgcn_exp2f(x1);
                const float p2 = __builtin_amdgcn_exp2f(x2);
                const float p3 = __builtin_amdgcn_exp2f(x3);
                rs += (p0 + p1) + (p2 + p3);
                uint2 pk;
                pk.x = pack_bf16_ru(p0, p1);
                pk.y = pack_bf16_ru(p2, p3);
                *(uint2*)&pw[mt * 16 + (quad << 2)] = pk;
            }
            l_i += rs;

            // ---- O^T += V^T @ P^T ----
            __builtin_amdgcn_s_setprio(1);
            #pragma unroll
            for (int ks = 0; ks < 2; ++ks) {
                const short8 pf = *(const short8*)&Ps[((w << 4) + col) * 72 + ks * 32 + (quad << 3)];
                #pragma unroll
                for (int mt = 0; mt < 4; ++mt) {
                    const short8 vf = *(const short8*)&Vc[(mt * 16 + col) * 64 + (ks ? cs1 : cs0)];
                    oacc[mt] = __builtin_amdgcn_mfma_f32_16x16x32_bf16(vf, pf, oacc[mt], 0, 0, 0);
                }
            }
            __builtin_amdgcn_s_setprio(0);
        }
        cur ^= 1;
    }

    // ---- epilogue: reduce l across quads, normalize, store ----
    l_i += __shfl_xor(l_i, 16, 64);
    l_i += __shfl_xor(l_i, 32, 64);
    const float inv = 1.0f / l_i;
    unsigned short* yrow = yb + (size_t)(b * T + qg) * 1024 + (h << 6);
    #pragma unroll
    for (int mt = 0; mt < 4; ++mt) {
        ushort4 yv;
        yv.x = f2bf(oacc[mt][0] * inv);
        yv.y = f2bf(oacc[mt][1] * inv);
        yv.z = f2bf(oacc[mt][2] * inv);
        yv.w = f2bf(oacc[mt][3] * inv);
        *(ushort4*)&yrow[mt * 16 + (quad << 2)] = yv;
    }
}

// ======================================================================
extern "C" void kernel_launch(void* const* d_in, const int* in_sizes, int n_in,
                              void* d_out, int out_size, void* d_ws, size_t ws_size,
                              hipStream_t stream)
{
    const float* x      = (const float*)d_in[0];
    const float* cosp   = (const float*)d_in[1];
    const float* sinp   = (const float*)d_in[2];
    const float* W_attn = (const float*)d_in[3];
    const float* b_attn = (const float*)d_in[4];
    const float* W_proj = (const float*)d_in[5];
    const float* b_proj = (const float*)d_in[6];
    float* out = (float*)d_out;

    const int C = 1024, H = 16;
    const int T  = in_sizes[1] / 64;     // cos: (T, 64)
    const int BT = in_sizes[0] / C;      // B*T
    const int B  = BT / T;

    // workspace layout (ushort units unless noted)
    float2* csb          = (float2*)d_ws;                       // T*32 float2
    unsigned short* qkvb = (unsigned short*)(csb + (size_t)T * 32); // BT*3072
    unsigned short* xb   = qkvb + (size_t)BT * 3072;            // BT*1024
    unsigned short* Wab  = xb   + (size_t)BT * 1024;            // 3072*1024
    unsigned short* Wpb  = Wab  + (size_t)3072 * 1024;          // 1024*1024
    unsigned short* yb   = Wpb  + (size_t)1024 * 1024;          // BT*1024
    unsigned short* vtb  = yb   + (size_t)BT * 1024;            // BT*1024 (own slot: written by gemm_qkv while xb still live)

    const int castBlocks = BT * C / 1024;
    const int csBlocks   = T * 32 / 256;
    prep_cast_transpose<<<dim3(castBlocks + 4096 + csBlocks), dim3(256), 0, stream>>>(
        x, xb, BT * C, W_attn, Wab, W_proj, Wpb, cosp, sinp, csb, castBlocks);

    gemm_qkv<<<dim3(3 * C / 128, BT / 128), dim3(256), 0, stream>>>(
        xb, Wab, b_attn, qkvb, vtb, csb, BT, C, T);

    flash_attn_mfma<<<dim3(B * H, T / 128), dim3(512), 0, stream>>>(
        qkvb, vtb, yb, B, T);

    gemm_bf16_n64<<<dim3(C / 64, BT / 128), dim3(256), 0, stream>>>(
        yb, Wpb, b_proj, out, BT, C, C);
}

// Round 8
// 173.989 us; speedup vs baseline: 1.2212x; 1.0168x over previous
//
#include <hip/hip_runtime.h>
#include <math.h>

#define EPSV 1.1920929e-07f

typedef __attribute__((ext_vector_type(8))) short short8;
typedef __attribute__((ext_vector_type(4))) float f32x4;

__device__ __forceinline__ float bf2f(unsigned short u) {
    union { unsigned int i; float f; } c; c.i = ((unsigned int)u) << 16; return c.f;
}
__device__ __forceinline__ unsigned short f2bf(float f) {
    union { float f; unsigned int i; } c; c.f = f;
    unsigned int r = c.i + 0x7FFFu + ((c.i >> 16) & 1u);   // RNE
    return (unsigned short)(r >> 16);
}
// pack two f32 -> two bf16 (round-half-up) in one u32: low=a, high=b
__device__ __forceinline__ unsigned int pack_bf16_ru(float a, float b) {
    union { float f; unsigned int i; } ca, cb; ca.f = a; cb.f = b;
    return __builtin_amdgcn_perm(cb.i + 0x8000u, ca.i + 0x8000u, 0x07060302u);
}
// async global -> LDS, 16 B per lane (dest = wave-uniform base + lane*16)
__device__ __forceinline__ void async_lds16(const unsigned short* g, unsigned short* l) {
    __builtin_amdgcn_global_load_lds(
        (const __attribute__((address_space(1))) unsigned int*)g,
        (__attribute__((address_space(3))) unsigned int*)l, 16, 0, 0);
}

// ======================================================================
// MERGED prep: fp32->bf16 cast of x | transpose+cast of both weights |
// packed cos/sin table cs[T][32] (float2; cos[d]=cos[d%32] by concat).
// ======================================================================
__global__ __launch_bounds__(256) void prep_cast_transpose(
    const float* __restrict__ x, unsigned short* __restrict__ xb, int nCast,
    const float* __restrict__ Wa, unsigned short* __restrict__ Wat,
    const float* __restrict__ Wp, unsigned short* __restrict__ Wpt,
    const float* __restrict__ cosp, const float* __restrict__ sinp,
    float2* __restrict__ cs, int castBlocks)
{
    __shared__ float tile[32][33];
    const int bxg = blockIdx.x;
    if (bxg < castBlocks) {
        const int i = (bxg * 256 + threadIdx.x) * 4;
        if (i >= nCast) return;
        const float4 v = *(const float4*)&x[i];
        ushort4 o;
        o.x = f2bf(v.x); o.y = f2bf(v.y); o.z = f2bf(v.z); o.w = f2bf(v.w);
        *(ushort4*)&xb[i] = o;
        return;
    }
    if (bxg >= castBlocks + 4096) {   // cs table part
        const int i = (bxg - castBlocks - 4096) * 256 + threadIdx.x;
        const int tp = i >> 5, dp = i & 31;
        cs[i] = make_float2(cosp[tp * 64 + dp], sinp[tp * 64 + dp]);
        return;
    }
    const int r0 = bxg - castBlocks;
    int bx = r0 & 127;                      // 0..127
    const int by = r0 >> 7;                 // 0..31
    const float* W; unsigned short* Wt; int N;
    if (bx < 96) { W = Wa; Wt = Wat; N = 3072; }
    else         { W = Wp; Wt = Wpt; N = 1024; bx -= 96; }
    const int n0 = bx * 32, k0 = by * 32;
    const int r = threadIdx.x >> 3, c4 = (threadIdx.x & 7) * 4;
    const float4 v = *(const float4*)&W[(size_t)(k0 + r) * N + n0 + c4];
    tile[r][c4 + 0] = v.x; tile[r][c4 + 1] = v.y;
    tile[r][c4 + 2] = v.z; tile[r][c4 + 3] = v.w;
    __syncthreads();
    ushort4 o;
    o.x = f2bf(tile[c4 + 0][r]); o.y = f2bf(tile[c4 + 1][r]);
    o.z = f2bf(tile[c4 + 2][r]); o.w = f2bf(tile[c4 + 3][r]);
    *(ushort4*)&Wt[(size_t)(n0 + r) * 1024 + k0 + c4] = o;
}

// ======================================================================
// FUSED qkv GEMM (N=3072) with fused RMSNorm+RoPE / V-transpose epilogue
// (R7-verified). R8: k-loop converted 1-phase -> 2-PHASE ping-pong:
// BK=32 double-buffer (As[2]/Bs[2], same 32KB footprint / 3 blocks/CU);
// each __syncthreads' vmcnt drain now retires loads issued a FULL STEP
// earlier (hidden under that step's ds_read+MFMA), instead of loads
// issued immediately before the barrier (fully-exposed latency).
// ======================================================================
__global__ __launch_bounds__(256) void gemm_qkv(
    const unsigned short* __restrict__ A,
    const unsigned short* __restrict__ Bt,
    const float* __restrict__ bias,
    unsigned short* __restrict__ qkv,
    unsigned short* __restrict__ vt,
    const float2* __restrict__ cs,
    int M, int K, int T)
{
    const int N = 3072;
    // As[2][128][32]: [0,8192)  Bs[2][128][32]: [8192,16384)  (ushort idx)
    // vtile[128][136] (17408 ushorts) overlays everything in the V epilogue.
    __shared__ __align__(16) unsigned short smem[17408];

    const int t    = threadIdx.x;
    const int lane = t & 63;
    const int wv   = t >> 6;
    const int wrow = (wv >> 1) * 64;
    const int wcol = (wv & 1) * 64;
    const int m0 = blockIdx.y * 128;
    const int n0 = blockIdx.x * 128;
    const int col  = lane & 15;
    const int quad = lane >> 4;

    // staging: 2 asyncs per operand per step; rows (wv*16 + lane/4) and +64
    const int srw = lane >> 2;              // 0..15
    const int sck = (lane & 3) << 3;        // chunk*8
    const unsigned short* aP0 = A  + (size_t)(m0 + (wv << 4) + srw) * K + sck;
    const unsigned short* aP1 = aP0 + (size_t)64 * K;
    const unsigned short* bP0 = Bt + (size_t)(n0 + (wv << 4) + srw) * K + sck;
    const unsigned short* bP1 = bP0 + (size_t)64 * K;
    const int stoff = (wv << 9) + (lane << 3);   // linear: lane*16B per wave
    unsigned short* aD = smem + stoff;
    unsigned short* bD = smem + 8192 + stoff;

    f32x4 acc[4][4];
    #pragma unroll
    for (int i = 0; i < 4; ++i)
        #pragma unroll
        for (int j = 0; j < 4; ++j)
            acc[i][j] = (f32x4){0.f, 0.f, 0.f, 0.f};

    // prologue: stage k-step 0 into buffer 0
    async_lds16(aP0, aD);        async_lds16(aP1, aD + 2048);
    async_lds16(bP0, bD);        async_lds16(bP1, bD + 2048);
    aP0 += 32; aP1 += 32; bP0 += 32; bP1 += 32;

    const int NK = K >> 5;                  // 32 steps of BK=32
    for (int kt = 0; kt < NK; ++kt) {
        __syncthreads();   // drains step kt's loads (issued one step ago)
        if (kt + 1 < NK) {
            const int nb = ((kt + 1) & 1) << 12;   // *4096 ushorts
            async_lds16(aP0, aD + nb);  async_lds16(aP1, aD + nb + 2048);
            async_lds16(bP0, bD + nb);  async_lds16(bP1, bD + nb + 2048);
            aP0 += 32; aP1 += 32; bP0 += 32; bP1 += 32;
        }
        const unsigned short* Ac = smem + ((kt & 1) << 12);
        const unsigned short* Bc = smem + 8192 + ((kt & 1) << 12);
        short8 af[4], bf[4];
        #pragma unroll
        for (int mt = 0; mt < 4; ++mt)
            af[mt] = *(const short8*)&Ac[(wrow + mt * 16 + col) * 32 + (quad << 3)];
        #pragma unroll
        for (int nt = 0; nt < 4; ++nt)
            bf[nt] = *(const short8*)&Bc[(wcol + nt * 16 + col) * 32 + (quad << 3)];
        #pragma unroll
        for (int mt = 0; mt < 4; ++mt)
            #pragma unroll
            for (int nt = 0; nt < 4; ++nt)
                acc[mt][nt] = __builtin_amdgcn_mfma_f32_16x16x32_bf16(
                    af[mt], bf[nt], acc[mt][nt], 0, 0, 0);
    }

    // ---- bias (all paths) ----
    #pragma unroll
    for (int nt = 0; nt < 4; ++nt) {
        const float bv = bias[n0 + wcol + nt * 16 + col];
        #pragma unroll
        for (int mt = 0; mt < 4; ++mt)
            #pragma unroll
            for (int r = 0; r < 4; ++r)
                acc[mt][nt][r] += bv;
    }

    const int b     = m0 / T;          // batch (tile never spans batches)
    const int tpos0 = m0 - b * T;

    if (n0 < 2048) {
        // ---- q/k: RMSNorm + RoPE, store bf16 to qkv ----
        const int n_lin = n0 + wcol;
        const float scale = (n_lin < 1024) ? 0.18033688011112042f : 1.0f; // log2e/8 for q
        #pragma unroll
        for (int mt = 0; mt < 4; ++mt) {
            #pragma unroll
            for (int r = 0; r < 4; ++r) {
                float ss = acc[mt][0][r] * acc[mt][0][r]
                         + acc[mt][1][r] * acc[mt][1][r]
                         + acc[mt][2][r] * acc[mt][2][r]
                         + acc[mt][3][r] * acc[mt][3][r];
                ss += __shfl_xor(ss, 1, 64);
                ss += __shfl_xor(ss, 2, 64);
                ss += __shfl_xor(ss, 4, 64);
                ss += __shfl_xor(ss, 8, 64);
                const float rn = rsqrtf(ss * (1.0f / 64.0f) + EPSV) * scale;
                const int tpos = tpos0 + wrow + mt * 16 + (quad << 2) + r;
                const float2 c0 = cs[tpos * 32 + col];
                const float2 c1 = cs[tpos * 32 + 16 + col];
                const float o0 = (acc[mt][0][r] * c0.x - acc[mt][2][r] * c0.y) * rn;
                const float o1 = (acc[mt][1][r] * c1.x - acc[mt][3][r] * c1.y) * rn;
                const float o2 = (acc[mt][2][r] * c0.x + acc[mt][0][r] * c0.y) * rn;
                const float o3 = (acc[mt][3][r] * c1.x + acc[mt][1][r] * c1.y) * rn;
                const int m = m0 + wrow + mt * 16 + (quad << 2) + r;
                unsigned short* qr = qkv + (size_t)m * N + n_lin + col;
                qr[0]  = f2bf(o0);
                qr[16] = f2bf(o1);
                qr[32] = f2bf(o2);
                qr[48] = f2bf(o3);
            }
        }
    } else {
        // ---- v: transpose via LDS bounce, store to vt[bh*64+d][T] ----
        unsigned short (*vtile)[136] = (unsigned short(*)[136])smem;
        __syncthreads();   // staging buffers dead; safe to repurpose
        #pragma unroll
        for (int nt = 0; nt < 4; ++nt)
            #pragma unroll
            for (int mt = 0; mt < 4; ++mt)
                #pragma unroll
                for (int r = 0; r < 4; ++r)
                    vtile[wcol + nt * 16 + col][wrow + mt * 16 + (quad << 2) + r]
                        = f2bf(acc[mt][nt][r]);
        __syncthreads();
        const int td = t >> 4;          // 0..15
        const int mloc = (t & 15) << 3; // 0,8,..,120
        const int h2base = (n0 - 2048) >> 6;
        #pragma unroll
        for (int i = 0; i < 8; ++i) {
            const int dl = td + i * 16;
            const short8 o = *(const short8*)&vtile[dl][mloc];
            const int h2 = h2base + (dl >> 6);
            const size_t row = ((size_t)(b * 16 + h2) << 6) + (dl & 63);
            *(short8*)&vt[row * T + tpos0 + mloc] = o;
        }
    }
}

// ======================================================================
// bf16 MFMA GEMM, 128(M) x 64(N) (skinny-N gemm2), fp32 out.
// R8: same 1-phase -> 2-phase BK=32 ping-pong conversion.
// ======================================================================
__global__ __launch_bounds__(256) void gemm_bf16_n64(
    const unsigned short* __restrict__ A,
    const unsigned short* __restrict__ Bt,
    const float* __restrict__ bias,
    float* __restrict__ C,
    int M, int N, int K)
{
    // As[2][128][32]: [0,8192)  Bs[2][64][32]: [8192,12288)  (ushort idx)
    __shared__ __align__(16) unsigned short smem[12288];
    const int t    = threadIdx.x;
    const int lane = t & 63;
    const int wv   = t >> 6;
    const int wrow = wv << 5;
    const int m0 = blockIdx.y * 128;
    const int n0 = blockIdx.x * 64;
    const int col  = lane & 15;
    const int quad = lane >> 4;

    const int srw = lane >> 2;
    const int sck = (lane & 3) << 3;
    const unsigned short* aP0 = A  + (size_t)(m0 + (wv << 4) + srw) * K + sck;
    const unsigned short* aP1 = aP0 + (size_t)64 * K;
    const unsigned short* bP0 = Bt + (size_t)(n0 + (wv << 4) + srw) * K + sck;
    const int stoff = (wv << 9) + (lane << 3);
    unsigned short* aD = smem + stoff;
    unsigned short* bD = smem + 8192 + stoff;

    f32x4 acc[2][4];
    #pragma unroll
    for (int i = 0; i < 2; ++i)
        #pragma unroll
        for (int j = 0; j < 4; ++j)
            acc[i][j] = (f32x4){0.f, 0.f, 0.f, 0.f};

    // prologue
    async_lds16(aP0, aD);  async_lds16(aP1, aD + 2048);
    async_lds16(bP0, bD);
    aP0 += 32; aP1 += 32; bP0 += 32;

    const int NK = K >> 5;
    for (int kt = 0; kt < NK; ++kt) {
        __syncthreads();
        if (kt + 1 < NK) {
            const int nbA = ((kt + 1) & 1) << 12;   // *4096
            const int nbB = ((kt + 1) & 1) << 11;   // *2048
            async_lds16(aP0, aD + nbA);  async_lds16(aP1, aD + nbA + 2048);
            async_lds16(bP0, bD + nbB);
            aP0 += 32; aP1 += 32; bP0 += 32;
        }
        const unsigned short* Ac = smem + ((kt & 1) << 12);
        const unsigned short* Bc = smem + 8192 + ((kt & 1) << 11);
        short8 af[2], bf[4];
        #pragma unroll
        for (int mt = 0; mt < 2; ++mt)
            af[mt] = *(const short8*)&Ac[(wrow + mt * 16 + col) * 32 + (quad << 3)];
        #pragma unroll
        for (int nt = 0; nt < 4; ++nt)
            bf[nt] = *(const short8*)&Bc[(nt * 16 + col) * 32 + (quad << 3)];
        #pragma unroll
        for (int mt = 0; mt < 2; ++mt)
            #pragma unroll
            for (int nt = 0; nt < 4; ++nt)
                acc[mt][nt] = __builtin_amdgcn_mfma_f32_16x16x32_bf16(
                    af[mt], bf[nt], acc[mt][nt], 0, 0, 0);
    }

    const int rowq = quad << 2;
    #pragma unroll
    for (int nt = 0; nt < 4; ++nt) {
        const int n = n0 + nt * 16 + col;
        const float bv = bias[n];
        #pragma unroll
        for (int mt = 0; mt < 2; ++mt) {
            #pragma unroll
            for (int r = 0; r < 4; ++r) {
                const int m = m0 + wrow + mt * 16 + rowq + r;
                C[(size_t)m * N + n] = acc[mt][nt][r] + bv;
            }
        }
    }
}

// ======================================================================
// MFMA flash attention, FIXED-MAX softmax, q-tile 128, 8 waves x 16 q
// (R4/R5/R7 verified structure).
// ======================================================================
__global__ __launch_bounds__(512, 4) void flash_attn_mfma(
    const unsigned short* __restrict__ qkv,
    const unsigned short* __restrict__ vt,
    unsigned short* __restrict__ yb,
    int B, int T)
{
    const int bh = blockIdx.x;
    const int b  = bh >> 4, h = bh & 15;
    const int ny = (int)gridDim.y;
    const int y  = (int)blockIdx.y;
    const int hny = (ny + 1) >> 1;
    const int jq = (y < hny) ? (ny - 1 - y) : (y - hny);   // balanced pairing
    const int q0 = jq << 7;
    const int t  = threadIdx.x;
    const int lane = t & 63;
    const int w    = t >> 6;       // 0..7, each owns 16 q-rows
    const int col  = lane & 15;
    const int quad = lane >> 4;

    __shared__ __align__(16) unsigned short smem[25600];
    unsigned short* Kb = smem;
    unsigned short* Vb = smem + 8192;
    unsigned short* Ps = smem + 16384;

    const unsigned short* qb  = qkv + (size_t)b * T * 3072 + (h << 6);
    const unsigned short* kb  = qb + 1024;
    const unsigned short* vtb = vt + (size_t)bh * 64 * T;

    const int qw = q0 + (w << 4);        // wave's first q row (16 rows)
    const int qg = qw + col;             // lane's q row

    short8 qf[2];
    {
        const unsigned short* qrow = qb + (size_t)qg * 3072 + (quad << 3);
        qf[0] = *(const short8*)&qrow[0];
        qf[1] = *(const short8*)&qrow[32];
    }

    f32x4 oacc[4];
    #pragma unroll
    for (int i = 0; i < 4; ++i) oacc[i] = (f32x4){0.f, 0.f, 0.f, 0.f};
    float l_i = 0.f;   // per-lane partial; reduced across quads in epilogue

    const int sr = t >> 3;                         // row 0..63
    const int sg = (((t & 7) ^ (sr & 7)) << 3);    // swizzled chunk * 8 elems
    const unsigned short* kp = kb  + (size_t)sr * 3072 + sg;
    const unsigned short* vp = vtb + (size_t)sr * T + sg;

    async_lds16(kp, Kb + (t << 3));
    async_lds16(vp, Vb + (t << 3));
    kp += (size_t)64 * 3072; vp += 64;

    const int cs0 = ((quad ^ (col & 7)) << 3);
    const int cs1 = (((4 + quad) ^ (col & 7)) << 3);

    const int last_kt = (q0 + 127) >> 6;
    int cur = 0;
    for (int kt = 0; kt <= last_kt; ++kt) {
        const int k0 = kt << 6;
        __syncthreads();   // drains async -> buf[cur] ready; prev compute done
        if (kt < last_kt) {
            async_lds16(kp, Kb + ((cur ^ 1) << 12) + (t << 3));
            async_lds16(vp, Vb + ((cur ^ 1) << 12) + (t << 3));
            kp += (size_t)64 * 3072; vp += 64;
        }

        if (k0 <= qw + 15) {
            const unsigned short* Kc = Kb + (cur << 12);
            const unsigned short* Vc = Vb + (cur << 12);

            // ---- S^T = K @ Q^T ----
            f32x4 st[4];
            #pragma unroll
            for (int i = 0; i < 4; ++i) st[i] = (f32x4){0.f, 0.f, 0.f, 0.f};
            __builtin_amdgcn_s_setprio(1);
            #pragma unroll
            for (int ks = 0; ks < 2; ++ks)
                #pragma unroll
                for (int mt = 0; mt < 4; ++mt) {
                    const short8 kf = *(const short8*)&Kc[(mt * 16 + col) * 64 + (ks ? cs1 : cs0)];
                    st[mt] = __builtin_amdgcn_mfma_f32_16x16x32_bf16(kf, qf[ks], st[mt], 0, 0, 0);
                }
            __builtin_amdgcn_s_setprio(0);

            // ---- fixed-max softmax: p = exp2(s), mask via exp2(-inf)=0 ----
            const bool diag = (k0 + 63 > qw);
            unsigned short* pw = Ps + ((w << 4) + col) * 72;
            float rs = 0.f;
            #pragma unroll
            for (int mt = 0; mt < 4; ++mt) {
                float x0 = st[mt][0], x1 = st[mt][1];
                float x2 = st[mt][2], x3 = st[mt][3];
                if (diag) {
                    const int sbase = k0 + mt * 16 + (quad << 2);
                    if (sbase + 0 > qg) x0 = -INFINITY;
                    if (sbase + 1 > qg) x1 = -INFINITY;
                    if (sbase + 2 > qg) x2 = -INFINITY;
                    if (sbase + 3 > qg) x3 = -INFINITY;
                }
                const float p0 = __builtin_amdgcn_exp2f(x0);
                const float p1 = __builtin_amdgcn_exp2f(x1);
                const float p2 = __builtin_amdgcn_exp2f(x2);
                const float p3 = __builtin_amdgcn_exp2f(x3);
                rs += (p0 + p1) + (p2 + p3);
                uint2 pk;
                pk.x = pack_bf16_ru(p0, p1);
                pk.y = pack_bf16_ru(p2, p3);
                *(uint2*)&pw[mt * 16 + (quad << 2)] = pk;
            }
            l_i += rs;

            // ---- O^T += V^T @ P^T ----
            __builtin_amdgcn_s_setprio(1);
            #pragma unroll
            for (int ks = 0; ks < 2; ++ks) {
                const short8 pf = *(const short8*)&Ps[((w << 4) + col) * 72 + ks * 32 + (quad << 3)];
                #pragma unroll
                for (int mt = 0; mt < 4; ++mt) {
                    const short8 vf = *(const short8*)&Vc[(mt * 16 + col) * 64 + (ks ? cs1 : cs0)];
                    oacc[mt] = __builtin_amdgcn_mfma_f32_16x16x32_bf16(vf, pf, oacc[mt], 0, 0, 0);
                }
            }
            __builtin_amdgcn_s_setprio(0);
        }
        cur ^= 1;
    }

    // ---- epilogue: reduce l across quads, normalize, store ----
    l_i += __shfl_xor(l_i, 16, 64);
    l_i += __shfl_xor(l_i, 32, 64);
    const float inv = 1.0f / l_i;
    unsigned short* yrow = yb + (size_t)(b * T + qg) * 1024 + (h << 6);
    #pragma unroll
    for (int mt = 0; mt < 4; ++mt) {
        ushort4 yv;
        yv.x = f2bf(oacc[mt][0] * inv);
        yv.y = f2bf(oacc[mt][1] * inv);
        yv.z = f2bf(oacc[mt][2] * inv);
        yv.w = f2bf(oacc[mt][3] * inv);
        *(ushort4*)&yrow[mt * 16 + (quad << 2)] = yv;
    }
}

// ======================================================================
extern "C" void kernel_launch(void* const* d_in, const int* in_sizes, int n_in,
                              void* d_out, int out_size, void* d_ws, size_t ws_size,
                              hipStream_t stream)
{
    const float* x      = (const float*)d_in[0];
    const float* cosp   = (const float*)d_in[1];
    const float* sinp   = (const float*)d_in[2];
    const float* W_attn = (const float*)d_in[3];
    const float* b_attn = (const float*)d_in[4];
    const float* W_proj = (const float*)d_in[5];
    const float* b_proj = (const float*)d_in[6];
    float* out = (float*)d_out;

    const int C = 1024, H = 16;
    const int T  = in_sizes[1] / 64;     // cos: (T, 64)
    const int BT = in_sizes[0] / C;      // B*T
    const int B  = BT / T;

    // workspace layout (ushort units unless noted)
    float2* csb          = (float2*)d_ws;                       // T*32 float2
    unsigned short* qkvb = (unsigned short*)(csb + (size_t)T * 32); // BT*3072
    unsigned short* xb   = qkvb + (size_t)BT * 3072;            // BT*1024
    unsigned short* Wab  = xb   + (size_t)BT * 1024;            // 3072*1024
    unsigned short* Wpb  = Wab  + (size_t)3072 * 1024;          // 1024*1024
    unsigned short* yb   = Wpb  + (size_t)1024 * 1024;          // BT*1024
    unsigned short* vtb  = yb   + (size_t)BT * 1024;            // BT*1024

    const int castBlocks = BT * C / 1024;
    const int csBlocks   = T * 32 / 256;
    prep_cast_transpose<<<dim3(castBlocks + 4096 + csBlocks), dim3(256), 0, stream>>>(
        x, xb, BT * C, W_attn, Wab, W_proj, Wpb, cosp, sinp, csb, castBlocks);

    gemm_qkv<<<dim3(3 * C / 128, BT / 128), dim3(256), 0, stream>>>(
        xb, Wab, b_attn, qkvb, vtb, csb, BT, C, T);

    flash_attn_mfma<<<dim3(B * H, T / 128), dim3(512), 0, stream>>>(
        qkvb, vtb, yb, B, T);

    gemm_bf16_n64<<<dim3(C / 64, BT / 128), dim3(256), 0, stream>>>(
        yb, Wpb, b_proj, out, BT, C, C);
}